// Round 1
// baseline (1544.503 us; speedup 1.0000x reference)
//
#include <hip/hip_runtime.h>
#include <math.h>

// Problem constants
#define NB 4        // batch
#define NN 3072     // N = 48*64
#define NC 256      // C
#define CP 262      // C+6
#define MP 264      // padded C+6
#define HH 48
#define WW 64

__device__ __forceinline__ void fma4(float4& c, float a, float4 b) {
    c.x = fmaf(a, b.x, c.x);
    c.y = fmaf(a, b.y, c.y);
    c.z = fmaf(a, b.z, c.z);
    c.w = fmaf(a, b.w, c.w);
}

// ---------------- pos table: [NN][8] = (p3^2,p4^2,p3p4,p3,p4,1,0,0) ----------------
__global__ __launch_bounds__(256) void k_pos(float* __restrict__ posT) {
    int n = blockIdx.x * 256 + threadIdx.x;
    if (n >= NN) return;
    float p3 = -1.f + 2.f * (float)(n % HH) / 47.f;   // ys tiled
    float p4 = -1.f + 2.f * (float)(n / HH) / 63.f;   // xs repeat_interleave
    float* r = posT + (size_t)n * 8;
    r[0] = p3 * p3; r[1] = p4 * p4; r[2] = p3 * p4;
    r[3] = p3; r[4] = p4; r[5] = 1.f; r[6] = 0.f; r[7] = 0.f;
}

// ---------------- row stats: rm = rowmax, irs = 1/rowsum ----------------
__global__ __launch_bounds__(256) void k_rowstats(const float* __restrict__ corr,
                                                  float* __restrict__ rm,
                                                  float* __restrict__ irs) {
    const int n = blockIdx.x, b = blockIdx.y;
    const float4* p = (const float4*)(corr + ((size_t)b * NN + n) * NN);
    const int t = threadIdx.x;
    __shared__ float red[8];
    float4 v[3];
    float m = -3.4e38f;
#pragma unroll
    for (int i = 0; i < 3; i++) {
        v[i] = p[t + i * 256];
        m = fmaxf(m, fmaxf(fmaxf(v[i].x, v[i].y), fmaxf(v[i].z, v[i].w)));
    }
#pragma unroll
    for (int off = 32; off; off >>= 1) m = fmaxf(m, __shfl_xor(m, off));
    if ((t & 63) == 0) red[t >> 6] = m;
    __syncthreads();
    m = fmaxf(fmaxf(red[0], red[1]), fmaxf(red[2], red[3]));
    float s = 0.f;
#pragma unroll
    for (int i = 0; i < 3; i++)
        s += __expf(v[i].x - m) + __expf(v[i].y - m) + __expf(v[i].z - m) + __expf(v[i].w - m);
#pragma unroll
    for (int off = 32; off; off >>= 1) s += __shfl_xor(s, off);
    if ((t & 63) == 0) red[4 + (t >> 6)] = s;
    __syncthreads();
    if (t == 0) {
        float st = red[4] + red[5] + red[6] + red[7];
        rm[b * NN + n] = m;
        irs[b * NN + n] = 1.f / st;
    }
}

// ---------------- col stats partials (online max/sum over 384-row chunks) ----------------
__global__ __launch_bounds__(256) void k_colstats(const float* __restrict__ corr,
                                                  float* __restrict__ pM,
                                                  float* __restrict__ pS) {
    int m = blockIdx.x * 256 + threadIdx.x;
    int b = blockIdx.y;
    int chunk = blockIdx.z;
    const float* p = corr + (size_t)b * NN * NN + m;
    int r0 = chunk * 384;
    float mx = -3.4e38f, s = 0.f;
    for (int r = r0; r < r0 + 384; r++) {
        float x = p[(size_t)r * NN];
        float mn = fmaxf(mx, x);
        s = s * __expf(mx - mn) + __expf(x - mn);
        mx = mn;
    }
    pM[((size_t)chunk * NB + b) * NN + m] = mx;
    pS[((size_t)chunk * NB + b) * NN + m] = s;
}

// ---------------- combine col partials: cc = colmax + log(colsum) ----------------
__global__ __launch_bounds__(256) void k_colcombine(const float* __restrict__ pM,
                                                    const float* __restrict__ pS,
                                                    float* __restrict__ cc) {
    int idx = blockIdx.x * 256 + threadIdx.x;
    if (idx >= NB * NN) return;
    float mx = -3.4e38f, s = 0.f;
#pragma unroll
    for (int ch = 0; ch < 8; ch++) {
        float m2 = pM[(size_t)ch * NB * NN + idx];
        float s2 = pS[(size_t)ch * NB * NN + idx];
        float mn = fmaxf(mx, m2);
        s = s * __expf(mx - mn) + s2 * __expf(m2 - mn);
        mx = mn;
    }
    cc[idx] = mx + logf(s);
}

// ---------------- fused A-GEMM: Z1=A@x1, Z2=A@x2, P=A@pos (split-K=2) ----------------
// A[n,m] = exp(2a - rm[n] - cc[m]) * irs[n]   (irs applied at writeback)
// BM=32 rows/block, BK=16. grid: 768 = 4b * 96rowblk * 2split, XCD-affine decode.
__global__ __launch_bounds__(256) void k2_attn_gemm(const float* __restrict__ corr,
                                                    const float* __restrict__ x1g,
                                                    const float* __restrict__ x2g,
                                                    const float* __restrict__ rm,
                                                    const float* __restrict__ irs,
                                                    const float* __restrict__ cc,
                                                    const float* __restrict__ posT,
                                                    float* __restrict__ Z1a, float* __restrict__ Z2a, float* __restrict__ Pa,
                                                    float* __restrict__ Z1b, float* __restrict__ Z2b, float* __restrict__ Pb) {
    __shared__ float At[16][36];    // [k][row], padded stride 36 (16B-aligned rows)
    __shared__ float Xs[16][512];   // [k][c]: 0..255 = x1, 256..511 = x2
    __shared__ float Pred[4][32][6];

    // batch<->XCD affinity: batch b lives on XCDs {2b, 2b+1}
    int bid = blockIdx.x;
    int xcd = bid & 7, idx = bid >> 3;
    int b = xcd >> 1;
    int sub = (xcd & 1) + 2 * idx;     // 0..191
    int rowblk = sub % 96;
    int split = sub / 96;

    float* Z1 = split ? Z1b : Z1a;
    float* Z2 = split ? Z2b : Z2a;
    float* Pp = split ? Pb : Pa;

    const int t = threadIdx.x;
    const int n0 = rowblk * 32;
    const int kbeg = split * 1536;

    const int srow = t >> 3;          // 0..31 staging row
    const int scol = (t & 7) * 2;     // 0..14 staging k-col pair
    const int xkk = t >> 4;           // 0..15 X staging row
    const int xc = (t & 15) * 4;      // X staging col
    const int ct = t & 31, rt = t >> 5;
    const int lane = t & 63, wv = t >> 6;

    const float rmv = rm[b * NN + n0 + srow];
    const float* corrR = corr + ((size_t)b * NN + n0 + srow) * NN;
    const float* ccB = cc + b * NN;

    float4 acc[4][4];
#pragma unroll
    for (int i = 0; i < 4; i++)
#pragma unroll
        for (int q = 0; q < 4; q++) acc[i][q] = make_float4(0.f, 0.f, 0.f, 0.f);
    float pacc[6] = {0.f, 0.f, 0.f, 0.f, 0.f, 0.f};

    for (int k0 = kbeg; k0 < kbeg + 1536; k0 += 16) {
        float2 a2 = *(const float2*)(corrR + k0 + scol);
        float2 c2 = *(const float2*)(ccB + k0 + scol);
        const float* x1r = x1g + ((size_t)b * NN + k0 + xkk) * NC + xc;
        const float* x2r = x2g + ((size_t)b * NN + k0 + xkk) * NC + xc;
        float4 xv[8];
#pragma unroll
        for (int j = 0; j < 4; j++) {
            xv[j] = *(const float4*)(x1r + j * 64);
            xv[4 + j] = *(const float4*)(x2r + j * 64);
        }
        float e0 = __expf(2.f * a2.x - rmv - c2.x);
        float e1 = __expf(2.f * a2.y - rmv - c2.y);
        __syncthreads();
        At[scol][srow] = e0;
        At[scol + 1][srow] = e1;
#pragma unroll
        for (int j = 0; j < 4; j++) {
            *(float4*)&Xs[xkk][xc + j * 64] = xv[j];
            *(float4*)&Xs[xkk][256 + xc + j * 64] = xv[4 + j];
        }
        __syncthreads();
#pragma unroll
        for (int kk = 0; kk < 16; kk++) {
            float4 af = *(const float4*)&At[kk][rt * 4];
            float4 xf0 = *(const float4*)&Xs[kk][ct * 4];
            float4 xf1 = *(const float4*)&Xs[kk][128 + ct * 4];
            float4 xf2 = *(const float4*)&Xs[kk][256 + ct * 4];
            float4 xf3 = *(const float4*)&Xs[kk][384 + ct * 4];
#pragma unroll
            for (int i = 0; i < 4; i++) {
                float a = (&af.x)[i];
                fma4(acc[i][0], a, xf0);
                fma4(acc[i][1], a, xf1);
                fma4(acc[i][2], a, xf2);
                fma4(acc[i][3], a, xf3);
            }
        }
        // P = A @ pos : distributed, wave wv handles kk in [4wv,4wv+4), lanes<32 own rows
        if (lane < 32) {
#pragma unroll
            for (int k2 = 0; k2 < 4; k2++) {
                int kk = wv * 4 + k2;
                float av = At[kk][lane];
                const float* pr = posT + (size_t)(k0 + kk) * 8;
#pragma unroll
                for (int j = 0; j < 6; j++) pacc[j] += av * pr[j];
            }
        }
    }
    // write Z (scaled by 1/rowsum)
#pragma unroll
    for (int i = 0; i < 4; i++) {
        int n = n0 + rt * 4 + i;
        float s = irs[b * NN + n];
        size_t base = ((size_t)b * NN + n) * NC;
        float4 o0 = acc[i][0], o1 = acc[i][1], o2 = acc[i][2], o3 = acc[i][3];
        o0.x *= s; o0.y *= s; o0.z *= s; o0.w *= s;
        o1.x *= s; o1.y *= s; o1.z *= s; o1.w *= s;
        o2.x *= s; o2.y *= s; o2.z *= s; o2.w *= s;
        o3.x *= s; o3.y *= s; o3.z *= s; o3.w *= s;
        *(float4*)(Z1 + base + ct * 4) = o0;
        *(float4*)(Z1 + base + 128 + ct * 4) = o1;
        *(float4*)(Z2 + base + ct * 4) = o2;
        *(float4*)(Z2 + base + 128 + ct * 4) = o3;
    }
    if (lane < 32) {
#pragma unroll
        for (int j = 0; j < 6; j++) Pred[wv][lane][j] = pacc[j];
    }
    __syncthreads();
    if (t < 32) {
        float s = irs[b * NN + n0 + t];
        float* dst = Pp + ((size_t)b * NN + n0 + t) * 8;
#pragma unroll
        for (int j = 0; j < 6; j++)
            dst[j] = s * (Pred[0][t][j] + Pred[1][t][j] + Pred[2][t][j] + Pred[3][t][j]);
        dst[6] = 0.f; dst[7] = 0.f;
    }
}

// ---------------- elementwise add of split-K partials (A += B) ----------------
__global__ __launch_bounds__(256) void k_add(float* __restrict__ A, const float* __restrict__ B, int n4) {
    int i = blockIdx.x * 256 + threadIdx.x;
    if (i < n4) {
        float4 a = ((const float4*)A)[i], bb = ((const float4*)B)[i];
        a.x += bb.x; a.y += bb.y; a.z += bb.z; a.w += bb.w;
        ((float4*)A)[i] = a;
    }
}

// ---------------- M[r][c] = sum_n L[n][r] R[n][c]  (split-K=8) ----------------
// mat 0: L=v1=[x1|pos], R=Y1=[Z1|P]  -> M1 = G1        (out1 = G1^T W)
// mat 1: L=Y2=[Z2|P],  R=v2=[x2|pos] -> M2 = G2^T      (out2 = G2 W)
__global__ __launch_bounds__(256) void k3_outer(const float* __restrict__ x1g, const float* __restrict__ x2g,
                                                const float* __restrict__ posT,
                                                const float* __restrict__ Z1, const float* __restrict__ Z2,
                                                const float* __restrict__ P,
                                                float* __restrict__ Mpart) {
    __shared__ float Ls[16][68];
    __shared__ float Rs[16][68];
    int bx = blockIdx.x;            // 0..24
    int rtile = bx / 5, ctile = bx % 5;
    int mb = blockIdx.y;            // mat*4+b
    int mat = mb >> 2, b = mb & 3;
    int split = blockIdx.z;
    const float *Lm, *Le, *Rm, *Re;
    if (mat == 0) {
        Lm = x1g + (size_t)b * NN * NC; Le = posT;
        Rm = Z1 + (size_t)b * NN * NC;  Re = P + (size_t)b * NN * 8;
    } else {
        Lm = Z2 + (size_t)b * NN * NC;  Le = P + (size_t)b * NN * 8;
        Rm = x2g + (size_t)b * NN * NC; Re = posT;
    }
    int t = threadIdx.x;
    int tx = t & 15, ty = t >> 4;
    int sn = t >> 4, sc = (t & 15) * 4;
    int r0 = rtile * 64, c0 = ctile * 64;
    float acc[4][4] = {};
    int nbeg = split * 384;
    for (int n0 = nbeg; n0 < nbeg + 384; n0 += 16) {
        int n = n0 + sn;
        float4 lv, rv;
        int cL = r0 + sc;
        if (cL < 256)      lv = *(const float4*)(Lm + (size_t)n * NC + cL);
        else if (cL < 264) lv = *(const float4*)(Le + (size_t)n * 8 + (cL - 256));
        else               lv = make_float4(0.f, 0.f, 0.f, 0.f);
        int cR = c0 + sc;
        if (cR < 256)      rv = *(const float4*)(Rm + (size_t)n * NC + cR);
        else if (cR < 264) rv = *(const float4*)(Re + (size_t)n * 8 + (cR - 256));
        else               rv = make_float4(0.f, 0.f, 0.f, 0.f);
        __syncthreads();
        *(float4*)&Ls[sn][sc] = lv;
        *(float4*)&Rs[sn][sc] = rv;
        __syncthreads();
#pragma unroll
        for (int kk = 0; kk < 16; kk++) {
            float4 lf = *(const float4*)&Ls[kk][ty * 4];
            float4 rf = *(const float4*)&Rs[kk][tx * 4];
#pragma unroll
            for (int i = 0; i < 4; i++)
#pragma unroll
                for (int j = 0; j < 4; j++)
                    acc[i][j] = fmaf((&lf.x)[i], (&rf.x)[j], acc[i][j]);
        }
    }
    float* Mp = Mpart + ((size_t)mb * 8 + split) * (MP * MP);
#pragma unroll
    for (int i = 0; i < 4; i++) {
        int r = r0 + ty * 4 + i;
        int c = c0 + tx * 4;
        if (r < MP && c < MP)
            *(float4*)(Mp + (size_t)r * MP + c) = make_float4(acc[i][0], acc[i][1], acc[i][2], acc[i][3]);
    }
}

// ---------------- combine M split partials ----------------
__global__ __launch_bounds__(256) void k_mcombine(const float* __restrict__ Mpart, float* __restrict__ M) {
    const int per = MP * MP;  // 69696
    int f4 = blockIdx.x * 256 + threadIdx.x;
    if (f4 >= (8 * per) / 4) return;
    int e = f4 * 4;
    int mb = e / per;
    int off = e - mb * per;
    const float* src = Mpart + (size_t)mb * 8 * per + off;
    float4 s = make_float4(0.f, 0.f, 0.f, 0.f);
#pragma unroll
    for (int sp = 0; sp < 8; sp++) {
        float4 v = *(const float4*)(src + (size_t)sp * per);
        s.x += v.x; s.y += v.y; s.z += v.z; s.w += v.w;
    }
    *(float4*)(M + (size_t)mb * per + off) = s;
}

// ---------------- projection: out[i][j] = b[j] + sum_k M[k][i] W[k][j] ----------------
__global__ __launch_bounds__(256) void k4_proj(const float* __restrict__ M, const float* __restrict__ Wp,
                                               const float* __restrict__ bp, float* __restrict__ out) {
    int i0 = blockIdx.x * 16;
    int b = blockIdx.y;
    int mat = blockIdx.z;           // 0: M1 -> out1 (second half); 1: M2 -> out2 (first half)
    const float* Mp = M + (size_t)(mat * 4 + b) * (MP * MP);
    int t = threadIdx.x;
    int jt = t & 63, it = t >> 6;
    int j = jt * 4;
    float4 a0 = make_float4(0.f, 0.f, 0.f, 0.f), a1 = a0, a2 = a0, a3 = a0;
#pragma unroll 2
    for (int k = 0; k < CP; k++) {
        float4 w = *(const float4*)(Wp + (size_t)k * NC + j);
        float4 g = *(const float4*)(Mp + (size_t)k * MP + i0 + it * 4);
        fma4(a0, g.x, w); fma4(a1, g.y, w); fma4(a2, g.z, w); fma4(a3, g.w, w);
    }
    float4 bb = *(const float4*)(bp + j);
    a0.x += bb.x; a0.y += bb.y; a0.z += bb.z; a0.w += bb.w;
    a1.x += bb.x; a1.y += bb.y; a1.z += bb.z; a1.w += bb.w;
    a2.x += bb.x; a2.y += bb.y; a2.z += bb.z; a2.w += bb.w;
    a3.x += bb.x; a3.y += bb.y; a3.z += bb.z; a3.w += bb.w;
    float* ob = out + (mat == 0 ? (size_t)NB * CP * NC : (size_t)0) + (size_t)b * CP * NC;
    int i = i0 + it * 4;
    if (i + 0 < CP) *(float4*)(ob + (size_t)(i + 0) * NC + j) = a0;
    if (i + 1 < CP) *(float4*)(ob + (size_t)(i + 1) * NC + j) = a1;
    if (i + 2 < CP) *(float4*)(ob + (size_t)(i + 2) * NC + j) = a2;
    if (i + 3 < CP) *(float4*)(ob + (size_t)(i + 3) * NC + j) = a3;
}

extern "C" void kernel_launch(void* const* d_in, const int* in_sizes, int n_in,
                              void* d_out, int out_size, void* d_ws, size_t ws_size,
                              hipStream_t stream) {
    const float* x1 = (const float*)d_in[0];
    const float* x2 = (const float*)d_in[1];
    const float* corr = (const float*)d_in[2];
    const float* Wp = (const float*)d_in[3];
    const float* bp = (const float*)d_in[4];
    float* out = (float*)d_out;
    float* w = (float*)d_ws;

    size_t o = 0;
    float* rm = w + o;    o += NB * NN;
    float* irs = w + o;   o += NB * NN;
    float* cc = w + o;    o += NB * NN;
    float* pM = w + o;    o += 8 * NB * NN;
    float* pS = w + o;    o += 8 * NB * NN;
    float* posT = w + o;  o += NN * 8;
    float* Z1a = w + o;   o += (size_t)NB * NN * NC;
    float* Z2a = w + o;   o += (size_t)NB * NN * NC;
    float* Pa = w + o;    o += NB * NN * 8;
    float* Z1b = w + o;   o += (size_t)NB * NN * NC;
    float* Z2b = w + o;   o += (size_t)NB * NN * NC;
    float* Pb = w + o;    o += NB * NN * 8;
    float* Mpart = w + o; o += (size_t)8 * 8 * MP * MP;
    float* M = w + o;     o += (size_t)8 * MP * MP;
    // total ~18.1M floats (~72 MB) of workspace

    k_pos<<<dim3(12), dim3(256), 0, stream>>>(posT);
    k_rowstats<<<dim3(NN, NB), dim3(256), 0, stream>>>(corr, rm, irs);
    k_colstats<<<dim3(12, NB, 8), dim3(256), 0, stream>>>(corr, pM, pS);
    k_colcombine<<<dim3(48), dim3(256), 0, stream>>>(pM, pS, cc);
    k2_attn_gemm<<<dim3(768), dim3(256), 0, stream>>>(corr, x1, x2, rm, irs, cc, posT,
                                                      Z1a, Z2a, Pa, Z1b, Z2b, Pb);
    // Z1a+=Z1b, Z2a+=Z2b, Pa+=Pb (contiguous region)
    k_add<<<dim3(6240), dim3(256), 0, stream>>>(Z1a, Z1b, (2 * NB * NN * NC + NB * NN * 8) / 4);
    k3_outer<<<dim3(25, 8, 8), dim3(256), 0, stream>>>(x1, x2, posT, Z1a, Z2a, Pa, Mpart);
    k_mcombine<<<dim3(545), dim3(256), 0, stream>>>(Mpart, M);
    k4_proj<<<dim3(17, NB, 2), dim3(256), 0, stream>>>(M, Wp, bp, out);
}

// Round 2
// 437.543 us; speedup vs baseline: 3.5299x; 3.5299x over previous
//
#include <hip/hip_runtime.h>
#include <math.h>

// Problem constants
#define NB 4        // batch
#define NN 3072     // N = 48*64
#define NC 256      // C
#define CP 262      // C+6
#define MP 264      // padded C+6
#define HH 48
#define WW 64
#define KG 384      // NN/8 k-groups

typedef short short8 __attribute__((ext_vector_type(8)));
typedef float f32x4 __attribute__((ext_vector_type(4)));

__device__ __forceinline__ void fma4(float4& c, float a, float4 b) {
    c.x = fmaf(a, b.x, c.x);
    c.y = fmaf(a, b.y, c.y);
    c.z = fmaf(a, b.z, c.z);
    c.w = fmaf(a, b.w, c.w);
}

// ---------------- pos table: [NN][8] = (p3^2,p4^2,p3p4,p3,p4,1,0,0) ----------------
__global__ __launch_bounds__(256) void k_pos(float* __restrict__ posT) {
    int n = blockIdx.x * 256 + threadIdx.x;
    if (n >= NN) return;
    float p3 = -1.f + 2.f * (float)(n % HH) / 47.f;   // ys tiled
    float p4 = -1.f + 2.f * (float)(n / HH) / 63.f;   // xs repeat_interleave
    float* r = posT + (size_t)n * 8;
    r[0] = p3 * p3; r[1] = p4 * p4; r[2] = p3 * p4;
    r[3] = p3; r[4] = p4; r[5] = 1.f; r[6] = 0.f; r[7] = 0.f;
}

// ---------------- prep: split X=[x1|x2] to bf16 hi/lo in MFMA-frag order ----------------
// Xh/Xl layout: [b][kgrp=n/8][col 0..511][j=n%8]  (16B per (kgrp,col) = one B-frag slot)
__global__ __launch_bounds__(256) void k_prep(const float* __restrict__ x1,
                                              const float* __restrict__ x2,
                                              short* __restrict__ Xh, short* __restrict__ Xl) {
    int id = blockIdx.x * 256 + threadIdx.x;      // 4*384*512 = 786432
    int col = id & 511;
    int rest = id >> 9;
    int kg = rest % KG;
    int b = rest / KG;
    const float* src = (col < 256 ? x1 : x2) + ((size_t)b * NN + kg * 8) * NC + (col & 255);
    short* ph = Xh + (((size_t)b * KG + kg) * 512 + col) * 8;
    short* pl = Xl + (((size_t)b * KG + kg) * 512 + col) * 8;
#pragma unroll
    for (int j = 0; j < 8; j++) {
        float v = src[(size_t)j * NC];
        unsigned u = __float_as_uint(v);
        short hs = (short)(u >> 16);
        float r = v - __uint_as_float(u & 0xFFFF0000u);
        short ls = (short)(__float_as_uint(r) >> 16);
        ph[j] = hs;
        pl[j] = ls;
    }
}

// ---------------- row stats: rm = rowmax, irs = 1/rowsum ----------------
__global__ __launch_bounds__(256) void k_rowstats(const float* __restrict__ corr,
                                                  float* __restrict__ rm,
                                                  float* __restrict__ irs) {
    const int n = blockIdx.x, b = blockIdx.y;
    const float4* p = (const float4*)(corr + ((size_t)b * NN + n) * NN);
    const int t = threadIdx.x;
    __shared__ float red[8];
    float4 v[3];
    float m = -3.4e38f;
#pragma unroll
    for (int i = 0; i < 3; i++) {
        v[i] = p[t + i * 256];
        m = fmaxf(m, fmaxf(fmaxf(v[i].x, v[i].y), fmaxf(v[i].z, v[i].w)));
    }
#pragma unroll
    for (int off = 32; off; off >>= 1) m = fmaxf(m, __shfl_xor(m, off));
    if ((t & 63) == 0) red[t >> 6] = m;
    __syncthreads();
    m = fmaxf(fmaxf(red[0], red[1]), fmaxf(red[2], red[3]));
    float s = 0.f;
#pragma unroll
    for (int i = 0; i < 3; i++)
        s += __expf(v[i].x - m) + __expf(v[i].y - m) + __expf(v[i].z - m) + __expf(v[i].w - m);
#pragma unroll
    for (int off = 32; off; off >>= 1) s += __shfl_xor(s, off);
    if ((t & 63) == 0) red[4 + (t >> 6)] = s;
    __syncthreads();
    if (t == 0) {
        float st = red[4] + red[5] + red[6] + red[7];
        rm[b * NN + n] = m;
        irs[b * NN + n] = 1.f / st;
    }
}

// ---------------- col stats partials (online max/sum over 384-row chunks) ----------------
__global__ __launch_bounds__(256) void k_colstats(const float* __restrict__ corr,
                                                  float* __restrict__ pM,
                                                  float* __restrict__ pS) {
    int m = blockIdx.x * 256 + threadIdx.x;
    int b = blockIdx.y;
    int chunk = blockIdx.z;
    const float* p = corr + (size_t)b * NN * NN + m;
    int r0 = chunk * 384;
    float mx = -3.4e38f, s = 0.f;
    for (int r = r0; r < r0 + 384; r++) {
        float x = p[(size_t)r * NN];
        float mn = fmaxf(mx, x);
        s = s * __expf(mx - mn) + __expf(x - mn);
        mx = mn;
    }
    pM[((size_t)chunk * NB + b) * NN + m] = mx;
    pS[((size_t)chunk * NB + b) * NN + m] = s;
}

// ---------------- combine col partials: cc = colmax + log(colsum) ----------------
__global__ __launch_bounds__(256) void k_colcombine(const float* __restrict__ pM,
                                                    const float* __restrict__ pS,
                                                    float* __restrict__ cc) {
    int idx = blockIdx.x * 256 + threadIdx.x;
    if (idx >= NB * NN) return;
    float mx = -3.4e38f, s = 0.f;
#pragma unroll
    for (int ch = 0; ch < 8; ch++) {
        float m2 = pM[(size_t)ch * NB * NN + idx];
        float s2 = pS[(size_t)ch * NB * NN + idx];
        float mn = fmaxf(mx, m2);
        s = s * __expf(mx - mn) + s2 * __expf(m2 - mn);
        mx = mn;
    }
    cc[idx] = mx + logf(s);
}

// ---------------- fused MFMA A-GEMM: Z1=A@x1, Z2=A@x2, P=A@pos ----------------
// A[n,m] = exp(2a - rm[n] - cc[m]) * irs[n]  (irs at writeback).
// Split-bf16: e = eh + el, X = Xh + Xl; 3 MFMA passes (hh, hl, lh).
// BM=32, BN=512, 4 waves x (32r x 128c), no LDS, frag-direct global loads.
// mfma_f32_16x16x32_bf16 layout: A: lane(row=l&15, k=(l>>4)*8+j);
// B: lane(col=l&15, k=(l>>4)*8+j); D: lane(col=l&15, row=(l>>4)*4+r).
__global__ __launch_bounds__(256, 2) void k2_mfma(const float* __restrict__ corr,
                                                  const short* __restrict__ Xh,
                                                  const short* __restrict__ Xl,
                                                  const float* __restrict__ rm,
                                                  const float* __restrict__ irs,
                                                  const float* __restrict__ cc,
                                                  float* __restrict__ Z1, float* __restrict__ Z2,
                                                  float* __restrict__ Pa) {
    int bid = blockIdx.x;                 // 384 = 8 XCD * 48
    int xcd = bid & 7, sub = bid >> 3;
    int b = xcd >> 1;                     // 2 XCDs per batch (X L2 affinity)
    int rowblk = (xcd & 1) + 2 * sub;     // 0..95
    int n0 = rowblk * 32;
    int t = threadIdx.x;
    int w = t >> 6, l = t & 63;
    int row16 = l & 15, slot = l >> 4;    // slot = k-group 0..3

    const float* ccB = cc + b * NN;
    const float rmv0 = rm[b * NN + n0 + row16];
    const float rmv1 = rm[b * NN + n0 + 16 + row16];
    const float* cr0 = corr + ((size_t)b * NN + n0 + row16) * NN;
    const float* cr1 = corr + ((size_t)b * NN + n0 + 16 + row16) * NN;
    const short* xh = Xh + (((size_t)b * KG + slot) * 512 + w * 128 + row16) * 8;
    const short* xl = Xl + (((size_t)b * KG + slot) * 512 + w * 128 + row16) * 8;

    f32x4 acc[2][8];
    const f32x4 zz = {0.f, 0.f, 0.f, 0.f};
#pragma unroll
    for (int rf = 0; rf < 2; rf++)
#pragma unroll
        for (int i = 0; i < 8; i++) acc[rf][i] = zz;
    float pacc[12];
#pragma unroll
    for (int x = 0; x < 12; x++) pacc[x] = 0.f;

    // prologue: prefetch corr + cc for k0 = 0
    f32x4 cA0 = *(const f32x4*)(cr0 + slot * 8);
    f32x4 cA1 = *(const f32x4*)(cr0 + slot * 8 + 4);
    f32x4 cB0 = *(const f32x4*)(cr1 + slot * 8);
    f32x4 cB1 = *(const f32x4*)(cr1 + slot * 8 + 4);
    f32x4 cc0 = *(const f32x4*)(ccB + slot * 8);
    f32x4 cc1 = *(const f32x4*)(ccB + slot * 8 + 4);

    for (int k0 = 0; k0 < 3072; k0 += 32) {
        // ---- B fragment loads (this k-step), L2-resident ----
        short8 Bh[8], Bl[8];
#pragma unroll
        for (int i = 0; i < 8; i++) {
            Bh[i] = *(const short8*)(xh + i * 128);
            Bl[i] = *(const short8*)(xl + i * 128);
        }
        // ---- exp + bf16 hi/lo split (A fragments in registers) ----
        float e0[8], e1[8];
        short8 Ah0, Al0, Ah1, Al1;
#pragma unroll
        for (int j = 0; j < 4; j++) {
            float ccj = cc0[j];
            float v0 = __expf(fmaf(2.f, cA0[j], -rmv0) - ccj);
            float v1 = __expf(fmaf(2.f, cB0[j], -rmv1) - ccj);
            e0[j] = v0; e1[j] = v1;
            unsigned u0 = __float_as_uint(v0);
            Ah0[j] = (short)(u0 >> 16);
            float r0f = v0 - __uint_as_float(u0 & 0xFFFF0000u);
            Al0[j] = (short)(__float_as_uint(r0f) >> 16);
            unsigned u1 = __float_as_uint(v1);
            Ah1[j] = (short)(u1 >> 16);
            float r1f = v1 - __uint_as_float(u1 & 0xFFFF0000u);
            Al1[j] = (short)(__float_as_uint(r1f) >> 16);
        }
#pragma unroll
        for (int j = 0; j < 4; j++) {
            float ccj = cc1[j];
            float v0 = __expf(fmaf(2.f, cA1[j], -rmv0) - ccj);
            float v1 = __expf(fmaf(2.f, cB1[j], -rmv1) - ccj);
            e0[4 + j] = v0; e1[4 + j] = v1;
            unsigned u0 = __float_as_uint(v0);
            Ah0[4 + j] = (short)(u0 >> 16);
            float r0f = v0 - __uint_as_float(u0 & 0xFFFF0000u);
            Al0[4 + j] = (short)(__float_as_uint(r0f) >> 16);
            unsigned u1 = __float_as_uint(v1);
            Ah1[4 + j] = (short)(u1 >> 16);
            float r1f = v1 - __uint_as_float(u1 & 0xFFFF0000u);
            Al1[4 + j] = (short)(__float_as_uint(r1f) >> 16);
        }
        // ---- prefetch next k-step corr + cc (clamped to avoid OOB) ----
        int kx = (k0 + 32 < 3072) ? (k0 + 32) : 0;
        cA0 = *(const f32x4*)(cr0 + kx + slot * 8);
        cA1 = *(const f32x4*)(cr0 + kx + slot * 8 + 4);
        cB0 = *(const f32x4*)(cr1 + kx + slot * 8);
        cB1 = *(const f32x4*)(cr1 + kx + slot * 8 + 4);
        cc0 = *(const f32x4*)(ccB + kx + slot * 8);
        cc1 = *(const f32x4*)(ccB + kx + slot * 8 + 4);
        // ---- MFMA: 3 passes x 2 rowfrags x 8 colfrags (independent accs inner) ----
#pragma unroll
        for (int i = 0; i < 8; i++) {
            acc[0][i] = __builtin_amdgcn_mfma_f32_16x16x32_bf16(Ah0, Bh[i], acc[0][i], 0, 0, 0);
            acc[1][i] = __builtin_amdgcn_mfma_f32_16x16x32_bf16(Ah1, Bh[i], acc[1][i], 0, 0, 0);
        }
#pragma unroll
        for (int i = 0; i < 8; i++) {
            acc[0][i] = __builtin_amdgcn_mfma_f32_16x16x32_bf16(Ah0, Bl[i], acc[0][i], 0, 0, 0);
            acc[1][i] = __builtin_amdgcn_mfma_f32_16x16x32_bf16(Ah1, Bl[i], acc[1][i], 0, 0, 0);
        }
#pragma unroll
        for (int i = 0; i < 8; i++) {
            acc[0][i] = __builtin_amdgcn_mfma_f32_16x16x32_bf16(Al0, Bh[i], acc[0][i], 0, 0, 0);
            acc[1][i] = __builtin_amdgcn_mfma_f32_16x16x32_bf16(Al1, Bh[i], acc[1][i], 0, 0, 0);
        }
        // ---- wave 0: P = A@pos on VALU (overlaps matrix pipe) ----
        if (w == 0) {
#pragma unroll
            for (int j = 0; j < 8; j++) {
                int k = k0 + slot * 8 + j;
                int ip4 = k / HH;
                int ip3 = k - ip4 * HH;
                float p3 = -1.f + 2.f * (float)ip3 / 47.f;
                float p4 = -1.f + 2.f * (float)ip4 / 63.f;
                float p33 = p3 * p3, p44 = p4 * p4, p34 = p3 * p4;
                float q0 = e0[j], q1 = e1[j];
                pacc[0] += q0 * p33; pacc[1] += q0 * p44; pacc[2] += q0 * p34;
                pacc[3] += q0 * p3;  pacc[4] += q0 * p4;  pacc[5] += q0;
                pacc[6] += q1 * p33; pacc[7] += q1 * p44; pacc[8] += q1 * p34;
                pacc[9] += q1 * p3;  pacc[10] += q1 * p4; pacc[11] += q1;
            }
        }
        xh += 4 * 512 * 8;   // advance 4 k-groups
        xl += 4 * 512 * 8;
    }

    // ---- epilogue: scale by 1/rowsum, write Z1/Z2 ----
#pragma unroll
    for (int rf = 0; rf < 2; rf++) {
        f32x4 sv = *(const f32x4*)(irs + b * NN + n0 + rf * 16 + slot * 4);
#pragma unroll
        for (int i = 0; i < 8; i++) {
            int col = w * 128 + i * 16 + row16;
            float* Zb = (col < 256) ? (Z1 + (size_t)b * NN * NC + col)
                                    : (Z2 + (size_t)b * NN * NC + (col - 256));
#pragma unroll
            for (int r = 0; r < 4; r++) {
                int n = n0 + rf * 16 + slot * 4 + r;
                Zb[(size_t)n * NC] = acc[rf][i][r] * sv[r];
            }
        }
    }
    // ---- wave 0: reduce P over k-slots, write Pa ----
    if (w == 0) {
#pragma unroll
        for (int x = 0; x < 12; x++) {
            float v = pacc[x];
            v += __shfl_xor(v, 16);
            v += __shfl_xor(v, 32);
            pacc[x] = v;
        }
        if (slot == 0) {
#pragma unroll
            for (int rf = 0; rf < 2; rf++) {
                int n = n0 + rf * 16 + row16;
                float s = irs[b * NN + n];
                float* dst = Pa + ((size_t)b * NN + n) * 8;
#pragma unroll
                for (int jj = 0; jj < 6; jj++) dst[jj] = s * pacc[rf * 6 + jj];
                dst[6] = 0.f;
                dst[7] = 0.f;
            }
        }
    }
}

// ---------------- M[r][c] = sum_n L[n][r] R[n][c]  (split-K=4) ----------------
__global__ __launch_bounds__(256) void k3_outer(const float* __restrict__ x1g, const float* __restrict__ x2g,
                                                const float* __restrict__ posT,
                                                const float* __restrict__ Z1, const float* __restrict__ Z2,
                                                const float* __restrict__ P,
                                                float* __restrict__ Mpart) {
    __shared__ float Ls[16][68];
    __shared__ float Rs[16][68];
    int bx = blockIdx.x;            // 0..24
    int rtile = bx / 5, ctile = bx % 5;
    int mb = blockIdx.y;            // mat*4+b
    int mat = mb >> 2, b = mb & 3;
    int split = blockIdx.z;         // 0..3
    const float *Lm, *Le, *Rm, *Re;
    if (mat == 0) {
        Lm = x1g + (size_t)b * NN * NC; Le = posT;
        Rm = Z1 + (size_t)b * NN * NC;  Re = P + (size_t)b * NN * 8;
    } else {
        Lm = Z2 + (size_t)b * NN * NC;  Le = P + (size_t)b * NN * 8;
        Rm = x2g + (size_t)b * NN * NC; Re = posT;
    }
    int t = threadIdx.x;
    int tx = t & 15, ty = t >> 4;
    int sn = t >> 4, sc = (t & 15) * 4;
    int r0 = rtile * 64, c0 = ctile * 64;
    float acc[4][4] = {};
    int nbeg = split * 768;
    for (int n0 = nbeg; n0 < nbeg + 768; n0 += 16) {
        int n = n0 + sn;
        float4 lv, rv;
        int cL = r0 + sc;
        if (cL < 256)      lv = *(const float4*)(Lm + (size_t)n * NC + cL);
        else if (cL < 264) lv = *(const float4*)(Le + (size_t)n * 8 + (cL - 256));
        else               lv = make_float4(0.f, 0.f, 0.f, 0.f);
        int cR = c0 + sc;
        if (cR < 256)      rv = *(const float4*)(Rm + (size_t)n * NC + cR);
        else if (cR < 264) rv = *(const float4*)(Re + (size_t)n * 8 + (cR - 256));
        else               rv = make_float4(0.f, 0.f, 0.f, 0.f);
        __syncthreads();
        *(float4*)&Ls[sn][sc] = lv;
        *(float4*)&Rs[sn][sc] = rv;
        __syncthreads();
#pragma unroll
        for (int kk = 0; kk < 16; kk++) {
            float4 lf = *(const float4*)&Ls[kk][ty * 4];
            float4 rf = *(const float4*)&Rs[kk][tx * 4];
#pragma unroll
            for (int i = 0; i < 4; i++)
#pragma unroll
                for (int j = 0; j < 4; j++)
                    acc[i][j] = fmaf((&lf.x)[i], (&rf.x)[j], acc[i][j]);
        }
    }
    float* Mp = Mpart + ((size_t)mb * 4 + split) * (MP * MP);
#pragma unroll
    for (int i = 0; i < 4; i++) {
        int r = r0 + ty * 4 + i;
        int c = c0 + tx * 4;
        if (r < MP && c < MP)
            *(float4*)(Mp + (size_t)r * MP + c) = make_float4(acc[i][0], acc[i][1], acc[i][2], acc[i][3]);
    }
}

// ---------------- combine M split partials ----------------
__global__ __launch_bounds__(256) void k_mcombine(const float* __restrict__ Mpart, float* __restrict__ M) {
    const int per = MP * MP;  // 69696
    int f4 = blockIdx.x * 256 + threadIdx.x;
    if (f4 >= (8 * per) / 4) return;
    int e = f4 * 4;
    int mb = e / per;
    int off = e - mb * per;
    const float* src = Mpart + (size_t)mb * 4 * per + off;
    float4 s = make_float4(0.f, 0.f, 0.f, 0.f);
#pragma unroll
    for (int sp = 0; sp < 4; sp++) {
        float4 v = *(const float4*)(src + (size_t)sp * per);
        s.x += v.x; s.y += v.y; s.z += v.z; s.w += v.w;
    }
    *(float4*)(M + (size_t)mb * per + off) = s;
}

// ---------------- projection: out[i][j] = b[j] + sum_k M[k][i] W[k][j] ----------------
__global__ __launch_bounds__(256) void k4_proj(const float* __restrict__ M, const float* __restrict__ Wp,
                                               const float* __restrict__ bp, float* __restrict__ out) {
    int i0 = blockIdx.x * 16;
    int b = blockIdx.y;
    int mat = blockIdx.z;
    const float* Mp = M + (size_t)(mat * 4 + b) * (MP * MP);
    int t = threadIdx.x;
    int jt = t & 63, it = t >> 6;
    int j = jt * 4;
    float4 a0 = make_float4(0.f, 0.f, 0.f, 0.f), a1 = a0, a2 = a0, a3 = a0;
#pragma unroll 2
    for (int k = 0; k < CP; k++) {
        float4 w = *(const float4*)(Wp + (size_t)k * NC + j);
        float4 g = *(const float4*)(Mp + (size_t)k * MP + i0 + it * 4);
        fma4(a0, g.x, w); fma4(a1, g.y, w); fma4(a2, g.z, w); fma4(a3, g.w, w);
    }
    float4 bb = *(const float4*)(bp + j);
    a0.x += bb.x; a0.y += bb.y; a0.z += bb.z; a0.w += bb.w;
    a1.x += bb.x; a1.y += bb.y; a1.z += bb.z; a1.w += bb.w;
    a2.x += bb.x; a2.y += bb.y; a2.z += bb.z; a2.w += bb.w;
    a3.x += bb.x; a3.y += bb.y; a3.z += bb.z; a3.w += bb.w;
    float* ob = out + (mat == 0 ? (size_t)NB * CP * NC : (size_t)0) + (size_t)b * CP * NC;
    int i = i0 + it * 4;
    if (i + 0 < CP) *(float4*)(ob + (size_t)(i + 0) * NC + j) = a0;
    if (i + 1 < CP) *(float4*)(ob + (size_t)(i + 1) * NC + j) = a1;
    if (i + 2 < CP) *(float4*)(ob + (size_t)(i + 2) * NC + j) = a2;
    if (i + 3 < CP) *(float4*)(ob + (size_t)(i + 3) * NC + j) = a3;
}

extern "C" void kernel_launch(void* const* d_in, const int* in_sizes, int n_in,
                              void* d_out, int out_size, void* d_ws, size_t ws_size,
                              hipStream_t stream) {
    const float* x1 = (const float*)d_in[0];
    const float* x2 = (const float*)d_in[1];
    const float* corr = (const float*)d_in[2];
    const float* Wp = (const float*)d_in[3];
    const float* bp = (const float*)d_in[4];
    float* out = (float*)d_out;
    float* w = (float*)d_ws;

    size_t o = 0;
    float* rm = w + o;    o += NB * NN;
    float* irs = w + o;   o += NB * NN;
    float* cc = w + o;    o += NB * NN;
    float* pM = w + o;    o += 8 * NB * NN;
    float* pS = w + o;    o += 8 * NB * NN;
    float* posT = w + o;  o += NN * 8;
    float* Z1 = w + o;    o += (size_t)NB * NN * NC;
    float* Z2 = w + o;    o += (size_t)NB * NN * NC;
    float* Pa = w + o;    o += NB * NN * 8;
    short* Xh = (short*)(w + o); o += (size_t)NB * KG * 512 * 8 / 2;   // shorts packed in float space
    short* Xl = (short*)(w + o); o += (size_t)NB * KG * 512 * 8 / 2;
    float* Mpart = w + o; o += (size_t)8 * 4 * MP * MP;
    float* M = w + o;     o += (size_t)8 * MP * MP;
    // total ~15.7M floats (~63 MB)

    k_pos<<<dim3(12), dim3(256), 0, stream>>>(posT);
    k_prep<<<dim3(3072), dim3(256), 0, stream>>>(x1, x2, Xh, Xl);
    k_rowstats<<<dim3(NN, NB), dim3(256), 0, stream>>>(corr, rm, irs);
    k_colstats<<<dim3(12, NB, 8), dim3(256), 0, stream>>>(corr, pM, pS);
    k_colcombine<<<dim3(48), dim3(256), 0, stream>>>(pM, pS, cc);
    k2_mfma<<<dim3(384), dim3(256), 0, stream>>>(corr, Xh, Xl, rm, irs, cc, Z1, Z2, Pa);
    k3_outer<<<dim3(25, 8, 4), dim3(256), 0, stream>>>(x1, x2, posT, Z1, Z2, Pa, Mpart);
    k_mcombine<<<dim3(545), dim3(256), 0, stream>>>(Mpart, M);
    k4_proj<<<dim3(17, NB, 2), dim3(256), 0, stream>>>(M, Wp, bp, out);
}

// Round 3
// 298.152 us; speedup vs baseline: 5.1803x; 1.4675x over previous
//
#include <hip/hip_runtime.h>
#include <math.h>

// Problem constants
#define NB 4        // batch
#define NN 3072     // N = 48*64
#define NC 256      // C
#define CP 262      // C+6
#define KG 384      // NN/8 k-groups
#define XW 528      // frag-array col width: x1(0..255) x2(256..511) pos/P(512..527)
#define MD 272      // padded M dim (17 frags * 16)
#define K3S 6       // k3 split-K
#define HH 48
#define WW 64

typedef short short8 __attribute__((ext_vector_type(8)));
typedef short short4v __attribute__((ext_vector_type(4)));
typedef float f32x4 __attribute__((ext_vector_type(4)));

__device__ __forceinline__ void bsplit(float v, short& h, short& l) {
    unsigned u = __float_as_uint(v);
    h = (short)(u >> 16);
    float r = v - __uint_as_float(u & 0xFFFF0000u);
    l = (short)(__float_as_uint(r) >> 16);
}

__device__ __forceinline__ void fma4(float4& c, float a, float4 b) {
    c.x = fmaf(a, b.x, c.x);
    c.y = fmaf(a, b.y, c.y);
    c.z = fmaf(a, b.z, c.z);
    c.w = fmaf(a, b.w, c.w);
}

// ---------------- prep: X=[x1|x2|pos] -> bf16 hi/lo in MFMA-frag order ----------------
// Layout: [b][kg=n/8][col 0..527][j=n%8]
__global__ __launch_bounds__(256) void k_prep(const float* __restrict__ x1,
                                              const float* __restrict__ x2,
                                              short* __restrict__ Xh, short* __restrict__ Xl) {
    int id = blockIdx.x * 256 + threadIdx.x;      // NB*KG*XW = 811008
    if (id >= NB * KG * XW) return;
    int col = id % XW;
    int rest = id / XW;
    int kg = rest % KG;
    int b = rest / KG;
    short* ph = Xh + (size_t)id * 8;
    short* pl = Xl + (size_t)id * 8;
    if (col < 512) {
        const float* src = (col < 256 ? x1 : x2) + ((size_t)b * NN + kg * 8) * NC + (col & 255);
#pragma unroll
        for (int j = 0; j < 8; j++) {
            short hs, ls;
            bsplit(src[(size_t)j * NC], hs, ls);
            ph[j] = hs; pl[j] = ls;
        }
    } else {
        int c = col - 512;
#pragma unroll
        for (int j = 0; j < 8; j++) {
            int k = kg * 8 + j;
            int ip4 = k / HH;
            int ip3 = k - ip4 * HH;
            float p3 = -1.f + 2.f * (float)ip3 / 47.f;
            float p4 = -1.f + 2.f * (float)ip4 / 63.f;
            float v = 0.f;
            if (c == 0) v = p3 * p3;
            else if (c == 1) v = p4 * p4;
            else if (c == 2) v = p3 * p4;
            else if (c == 3) v = p3;
            else if (c == 4) v = p4;
            else if (c == 5) v = 1.f;
            short hs, ls;
            bsplit(v, hs, ls);
            ph[j] = hs; pl[j] = ls;
        }
    }
}

// ---------------- row stats: rm = rowmax, irs = 1/rowsum ----------------
__global__ __launch_bounds__(256) void k_rowstats(const float* __restrict__ corr,
                                                  float* __restrict__ rm,
                                                  float* __restrict__ irs) {
    const int n = blockIdx.x, b = blockIdx.y;
    const float4* p = (const float4*)(corr + ((size_t)b * NN + n) * NN);
    const int t = threadIdx.x;
    __shared__ float red[8];
    float4 v[3];
    float m = -3.4e38f;
#pragma unroll
    for (int i = 0; i < 3; i++) {
        v[i] = p[t + i * 256];
        m = fmaxf(m, fmaxf(fmaxf(v[i].x, v[i].y), fmaxf(v[i].z, v[i].w)));
    }
#pragma unroll
    for (int off = 32; off; off >>= 1) m = fmaxf(m, __shfl_xor(m, off));
    if ((t & 63) == 0) red[t >> 6] = m;
    __syncthreads();
    m = fmaxf(fmaxf(red[0], red[1]), fmaxf(red[2], red[3]));
    float s = 0.f;
#pragma unroll
    for (int i = 0; i < 3; i++)
        s += __expf(v[i].x - m) + __expf(v[i].y - m) + __expf(v[i].z - m) + __expf(v[i].w - m);
#pragma unroll
    for (int off = 32; off; off >>= 1) s += __shfl_xor(s, off);
    if ((t & 63) == 0) red[4 + (t >> 6)] = s;
    __syncthreads();
    if (t == 0) {
        float st = red[4] + red[5] + red[6] + red[7];
        rm[b * NN + n] = m;
        irs[b * NN + n] = 1.f / st;
    }
}

// ---------------- col stats partials ----------------
__global__ __launch_bounds__(256) void k_colstats(const float* __restrict__ corr,
                                                  float* __restrict__ pM,
                                                  float* __restrict__ pS) {
    int m = blockIdx.x * 256 + threadIdx.x;
    int b = blockIdx.y;
    int chunk = blockIdx.z;
    const float* p = corr + (size_t)b * NN * NN + m;
    int r0 = chunk * 384;
    float mx = -3.4e38f, s = 0.f;
    for (int r = r0; r < r0 + 384; r++) {
        float x = p[(size_t)r * NN];
        float mn = fmaxf(mx, x);
        s = s * __expf(mx - mn) + __expf(x - mn);
        mx = mn;
    }
    pM[((size_t)chunk * NB + b) * NN + m] = mx;
    pS[((size_t)chunk * NB + b) * NN + m] = s;
}

// ---------------- combine col partials: cc = colmax + log(colsum) ----------------
__global__ __launch_bounds__(256) void k_colcombine(const float* __restrict__ pM,
                                                    const float* __restrict__ pS,
                                                    float* __restrict__ cc) {
    int idx = blockIdx.x * 256 + threadIdx.x;
    if (idx >= NB * NN) return;
    float mx = -3.4e38f, s = 0.f;
#pragma unroll
    for (int ch = 0; ch < 8; ch++) {
        float m2 = pM[(size_t)ch * NB * NN + idx];
        float s2 = pS[(size_t)ch * NB * NN + idx];
        float mn = fmaxf(mx, m2);
        s = s * __expf(mx - mn) + s2 * __expf(m2 - mn);
        mx = mn;
    }
    cc[idx] = mx + logf(s);
}

// ---------------- fused MFMA A-GEMM: Zarr = frag-layout bf16 split of [A@x1 | A@x2 | A@pos] ----
// A[n,m] = exp(2a - rm[n] - cc[m]) * irs[n] (irs at epilogue). Split-bf16 3-pass MFMA.
// 768 blocks: BM=32 rows; which=0 -> x1 cols (+pos frag on wave 0), which=1 -> x2 cols.
// exp+split computed once per block into dbuf LDS A-frag tile; raw s_barrier (no vmcnt drain).
__global__ __launch_bounds__(256, 3) void k2_mfma(const float* __restrict__ corr,
        const short* __restrict__ Xh, const short* __restrict__ Xl,
        const float* __restrict__ rm, const float* __restrict__ irs,
        const float* __restrict__ cc,
        short* __restrict__ Zh, short* __restrict__ Zl) {
    __shared__ short AH[2][128][8];
    __shared__ short AL[2][128][8];

    int bid = blockIdx.x;                    // 768 = 8 xcd * 96
    int xcd = bid & 7, sub = bid >> 3;       // sub 0..95
    int b = xcd >> 1;                        // batch on XCD pair
    int which = sub & 1;                     // 0: x1(+pos), 1: x2  (pair shares XCD -> corr L2 reuse)
    int rowblk = (xcd & 1) + ((sub >> 1) << 1);   // 0..95
    int n0 = rowblk * 32;
    int t = threadIdx.x;
    int w = t >> 6, l = t & 63;
    int row16 = l & 15, slot = l >> 4;
    bool posw = (which == 0) && (w == 0);

    // writer role: thread t -> row wr (0..31), k-quad wkq (0..7)
    int wr = t >> 3, wkq = t & 7;
    int widx = ((wr >> 4) << 6) + ((wkq >> 1) << 4) + (wr & 15);
    int wjb = (wkq & 1) << 2;

    const float* corrR = corr + ((size_t)b * NN + n0 + wr) * NN;
    const float* ccB = cc + (size_t)b * NN;
    const float rmv = rm[b * NN + n0 + wr];

    // B-frag base pointers (frag i at +i*128 shorts; frags are 16 cols apart)
    int cbase = which ? 256 : 0;
    int colb = cbase + w * 64 + row16;
    size_t off0 = ((size_t)(b * KG + slot) * XW + colb) * 8;
    const short* bph = Xh + off0;
    const short* bpl = Xl + off0;
    const short* pph = nullptr;
    const short* ppl = nullptr;
    if (posw) {
        size_t offp = ((size_t)(b * KG + slot) * XW + 512 + row16) * 8;
        pph = Xh + offp; ppl = Xl + offp;
    }
    const size_t BSTEP = (size_t)4 * XW * 8;  // 4 kg per 32-k step

    f32x4 acc[2][4];
    f32x4 accP[2];
    const f32x4 zz = {0.f, 0.f, 0.f, 0.f};
#pragma unroll
    for (int rf = 0; rf < 2; rf++) {
#pragma unroll
        for (int i = 0; i < 4; i++) acc[rf][i] = zz;
        accP[rf] = zz;
    }

#define EXPSPLIT(CV, CCV, AH_, AL_)                                        \
    {                                                                       \
        _Pragma("unroll") for (int q = 0; q < 4; q++) {                     \
            float e = __expf(fmaf(2.f, (CV)[q], -rmv) - (CCV)[q]);          \
            short hs, ls; bsplit(e, hs, ls);                                \
            (AH_)[q] = hs; (AL_)[q] = ls;                                   \
        }                                                                   \
    }

    // prologue
    f32x4 cv0 = *(const f32x4*)(corrR + wkq * 4);
    f32x4 cw0 = *(const f32x4*)(ccB + wkq * 4);
    short4v ah, al;
    EXPSPLIT(cv0, cw0, ah, al);
    f32x4 cbB = *(const f32x4*)(corrR + 32 + wkq * 4);   // k-step 1
    f32x4 ccbB = *(const f32x4*)(ccB + 32 + wkq * 4);
    f32x4 cbA = *(const f32x4*)(corrR + 64 + wkq * 4);   // k-step 2
    f32x4 ccbA = *(const f32x4*)(ccB + 64 + wkq * 4);

    short8 Bh[4], Bl[4], Pbh, Pbl;
#pragma unroll
    for (int i = 0; i < 4; i++) {
        Bh[i] = *(const short8*)(bph + i * 128);
        Bl[i] = *(const short8*)(bpl + i * 128);
    }
    if (posw) { Pbh = *(const short8*)pph; Pbl = *(const short8*)ppl; }

    int p = 0;

#define KSTEP(CB, CCB, IT)                                                  \
    {                                                                       \
        *(short4v*)&AH[p][widx][wjb] = ah;                                  \
        *(short4v*)&AL[p][widx][wjb] = al;                                  \
        asm volatile("s_waitcnt lgkmcnt(0)" ::: "memory");                  \
        __builtin_amdgcn_s_barrier();                                       \
        short8 Ah0 = *(const short8*)&AH[p][slot * 16 + row16][0];          \
        short8 Ah1 = *(const short8*)&AH[p][64 + slot * 16 + row16][0];     \
        short8 Al0 = *(const short8*)&AL[p][slot * 16 + row16][0];          \
        short8 Al1 = *(const short8*)&AL[p][64 + slot * 16 + row16][0];     \
        _Pragma("unroll") for (int i = 0; i < 4; i++) {                     \
            acc[0][i] = __builtin_amdgcn_mfma_f32_16x16x32_bf16(Ah0, Bh[i], acc[0][i], 0, 0, 0); \
            acc[1][i] = __builtin_amdgcn_mfma_f32_16x16x32_bf16(Ah1, Bh[i], acc[1][i], 0, 0, 0); \
        }                                                                   \
        if (posw) {                                                         \
            accP[0] = __builtin_amdgcn_mfma_f32_16x16x32_bf16(Ah0, Pbh, accP[0], 0, 0, 0); \
            accP[1] = __builtin_amdgcn_mfma_f32_16x16x32_bf16(Ah1, Pbh, accP[1], 0, 0, 0); \
        }                                                                   \
        _Pragma("unroll") for (int i = 0; i < 4; i++) {                     \
            acc[0][i] = __builtin_amdgcn_mfma_f32_16x16x32_bf16(Al0, Bh[i], acc[0][i], 0, 0, 0); \
            acc[1][i] = __builtin_amdgcn_mfma_f32_16x16x32_bf16(Al1, Bh[i], acc[1][i], 0, 0, 0); \
        }                                                                   \
        if (posw) {                                                         \
            accP[0] = __builtin_amdgcn_mfma_f32_16x16x32_bf16(Al0, Pbh, accP[0], 0, 0, 0); \
            accP[1] = __builtin_amdgcn_mfma_f32_16x16x32_bf16(Al1, Pbh, accP[1], 0, 0, 0); \
        }                                                                   \
        bph += BSTEP;                                                       \
        _Pragma("unroll") for (int i = 0; i < 4; i++)                       \
            Bh[i] = *(const short8*)(bph + i * 128);                        \
        if (posw) { pph += BSTEP; Pbh = *(const short8*)pph; }              \
        _Pragma("unroll") for (int i = 0; i < 4; i++) {                     \
            acc[0][i] = __builtin_amdgcn_mfma_f32_16x16x32_bf16(Ah0, Bl[i], acc[0][i], 0, 0, 0); \
            acc[1][i] = __builtin_amdgcn_mfma_f32_16x16x32_bf16(Ah1, Bl[i], acc[1][i], 0, 0, 0); \
        }                                                                   \
        if (posw) {                                                         \
            accP[0] = __builtin_amdgcn_mfma_f32_16x16x32_bf16(Ah0, Pbl, accP[0], 0, 0, 0); \
            accP[1] = __builtin_amdgcn_mfma_f32_16x16x32_bf16(Ah1, Pbl, accP[1], 0, 0, 0); \
        }                                                                   \
        bpl += BSTEP;                                                       \
        _Pragma("unroll") for (int i = 0; i < 4; i++)                       \
            Bl[i] = *(const short8*)(bpl + i * 128);                        \
        if (posw) { ppl += BSTEP; Pbl = *(const short8*)ppl; }              \
        EXPSPLIT(CB, CCB, ah, al);                                          \
        {                                                                   \
            int kf = (IT) * 32 + 96;                                        \
            if (kf > 3040) kf = 3040;                                       \
            CB = *(const f32x4*)(corrR + kf + wkq * 4);                     \
            CCB = *(const f32x4*)(ccB + kf + wkq * 4);                      \
        }                                                                   \
        p ^= 1;                                                             \
    }

    for (int it = 0; it < 96; it += 2) {
        KSTEP(cbB, ccbB, it);
        KSTEP(cbA, ccbA, it + 1);
    }
#undef KSTEP
#undef EXPSPLIT

    // epilogue: scale by 1/rowsum, bf16-split, write frag-layout Zarr
#pragma unroll
    for (int rf = 0; rf < 2; rf++) {
        f32x4 sv = *(const f32x4*)(irs + b * NN + n0 + rf * 16 + slot * 4);
        int kgz = rowblk * 4 + rf * 2 + (slot >> 1);
        int jb = (slot & 1) << 2;
#pragma unroll
        for (int i = 0; i < 4; i++) {
            int colv = cbase + (w * 4 + i) * 16 + row16;
            size_t off = ((size_t)(b * KG + kgz) * XW + colv) * 8 + jb;
            short4v zh, zl;
#pragma unroll
            for (int r = 0; r < 4; r++) {
                float vv = acc[rf][i][r] * sv[r];
                short hs, ls; bsplit(vv, hs, ls);
                zh[r] = hs; zl[r] = ls;
            }
            *(short4v*)(Zh + off) = zh;
            *(short4v*)(Zl + off) = zl;
        }
        if (posw) {
            size_t off = ((size_t)(b * KG + kgz) * XW + 512 + row16) * 8 + jb;
            short4v zh, zl;
#pragma unroll
            for (int r = 0; r < 4; r++) {
                float vv = accP[rf][r] * sv[r];
                short hs, ls; bsplit(vv, hs, ls);
                zh[r] = hs; zl[r] = ls;
            }
            *(short4v*)(Zh + off) = zh;
            *(short4v*)(Zl + off) = zl;
        }
    }
}

// ---------------- k3: M[r][c] = sum_n L[n][r] R[n][c] via MFMA (split-bf16, split-K=6) -------
// mat0: L = [x1|pos] (Xarr), R = [Z1|P] (Zarr), both frag slices at base 0 (+pos frag 512)
// mat1: L = [Z2|P]  (Zarr),  R = [x2|pos] (Xarr), bases 256 (+frag 512)
__global__ __launch_bounds__(256) void k3_mfma(const short* __restrict__ Xh, const short* __restrict__ Xl,
                                               const short* __restrict__ Zh, const short* __restrict__ Zl,
                                               float* __restrict__ Mpart) {
    int tile = blockIdx.x;              // 0..8 (3x3 frag tiles of [6,6,5])
    int rt = tile / 3, ct = tile % 3;
    int mb = blockIdx.y;                // mat*4+b
    int mat = mb >> 2, b = mb & 3;
    int split = blockIdx.z;             // 0..5, K=512 each

    const int O0[4] = {0, 6, 12, 17};
    int r0f = O0[rt], rNf = O0[rt + 1] - r0f;
    int c0f = O0[ct], cNf = O0[ct + 1] - c0f;

    int t = threadIdx.x;
    int w = t >> 6, l = t & 63;
    int row16 = l & 15, slot = l >> 4;
    int wr = w >> 1, wc = w & 1;
    int rh = (rNf + 1) >> 1;
    int rbeg = r0f + (wr ? rh : 0);
    int rcnt = wr ? (rNf - rh) : rh;     // <=3
    int chh = (cNf + 1) >> 1;
    int cbeg = c0f + (wc ? chh : 0);
    int ccnt = wc ? (cNf - chh) : chh;   // <=3

    const short *Ah_, *Al_, *Bh_, *Bl_;
    int abase, bbase;
    if (mat == 0) { Ah_ = Xh; Al_ = Xl; Bh_ = Zh; Bl_ = Zl; abase = 0; bbase = 0; }
    else          { Ah_ = Zh; Al_ = Zl; Bh_ = Xh; Bl_ = Xl; abase = 256; bbase = 256; }

    int acol[3], bcol[3];
#pragma unroll
    for (int i = 0; i < 3; i++) {
        int fa = rbeg + i;
        acol[i] = ((fa < 16) ? (abase + fa * 16) : 512) + row16;
        int fb = cbeg + i;
        bcol[i] = ((fb < 16) ? (bbase + fb * 16) : 512) + row16;
    }

    f32x4 acc[3][3];
    const f32x4 zz = {0.f, 0.f, 0.f, 0.f};
#pragma unroll
    for (int i = 0; i < 3; i++)
#pragma unroll
        for (int j = 0; j < 3; j++) acc[i][j] = zz;

    for (int it = 0; it < 16; it++) {
        int kg = split * 64 + it * 4 + slot;
        size_t base = (size_t)(b * KG + kg) * XW;
        short8 Ah[3], Al[3], Bhf[3], Blf[3];
#pragma unroll
        for (int i = 0; i < 3; i++) {
            if (i < rcnt) {
                Ah[i] = *(const short8*)(Ah_ + (base + acol[i]) * 8);
                Al[i] = *(const short8*)(Al_ + (base + acol[i]) * 8);
            }
            if (i < ccnt) {
                Bhf[i] = *(const short8*)(Bh_ + (base + bcol[i]) * 8);
                Blf[i] = *(const short8*)(Bl_ + (base + bcol[i]) * 8);
            }
        }
#pragma unroll
        for (int i = 0; i < 3; i++) {
            if (i < rcnt) {
#pragma unroll
                for (int j = 0; j < 3; j++) {
                    if (j < ccnt) {
                        acc[i][j] = __builtin_amdgcn_mfma_f32_16x16x32_bf16(Ah[i], Bhf[j], acc[i][j], 0, 0, 0);
                        acc[i][j] = __builtin_amdgcn_mfma_f32_16x16x32_bf16(Al[i], Bhf[j], acc[i][j], 0, 0, 0);
                        acc[i][j] = __builtin_amdgcn_mfma_f32_16x16x32_bf16(Ah[i], Blf[j], acc[i][j], 0, 0, 0);
                    }
                }
            }
        }
    }

    float* Mp = Mpart + (size_t)(mb * K3S + split) * (MD * MD);
#pragma unroll
    for (int i = 0; i < 3; i++) {
        if (i < rcnt) {
#pragma unroll
            for (int j = 0; j < 3; j++) {
                if (j < ccnt) {
                    int r = (rbeg + i) * 16 + slot * 4;
                    int c = (cbeg + j) * 16 + row16;
#pragma unroll
                    for (int q = 0; q < 4; q++)
                        Mp[(size_t)(r + q) * MD + c] = acc[i][j][q];
                }
            }
        }
    }
}

// ---------------- combine M split partials ----------------
__global__ __launch_bounds__(256) void k_mcombine(const float* __restrict__ Mpart, float* __restrict__ M) {
    const int per = MD * MD;  // 73984
    int f4 = blockIdx.x * 256 + threadIdx.x;
    if (f4 >= (8 * per) / 4) return;
    int e = f4 * 4;
    int mb = e / per;
    int off = e - mb * per;
    const float* src = Mpart + (size_t)mb * K3S * per + off;
    float4 s = make_float4(0.f, 0.f, 0.f, 0.f);
#pragma unroll
    for (int sp = 0; sp < K3S; sp++) {
        float4 v = *(const float4*)(src + (size_t)sp * per);
        s.x += v.x; s.y += v.y; s.z += v.z; s.w += v.w;
    }
    *(float4*)(M + (size_t)mb * per + off) = s;
}

// ---------------- projection: out[i][j] = b[j] + sum_k M[k][i] W[k][j] ----------------
__global__ __launch_bounds__(256) void k4_proj(const float* __restrict__ M, const float* __restrict__ Wp,
                                               const float* __restrict__ bp, float* __restrict__ out) {
    int i0 = blockIdx.x * 16;
    int b = blockIdx.y;
    int mat = blockIdx.z;           // 0: M1 -> out1 (second half); 1: M2 -> out2 (first half)
    const float* Mp = M + (size_t)(mat * 4 + b) * (MD * MD);
    int t = threadIdx.x;
    int jt = t & 63, it = t >> 6;
    int j = jt * 4;
    float4 a0 = make_float4(0.f, 0.f, 0.f, 0.f), a1 = a0, a2 = a0, a3 = a0;
#pragma unroll 2
    for (int k = 0; k < CP; k++) {
        float4 w = *(const float4*)(Wp + (size_t)k * NC + j);
        float4 g = *(const float4*)(Mp + (size_t)k * MD + i0 + it * 4);
        fma4(a0, g.x, w); fma4(a1, g.y, w); fma4(a2, g.z, w); fma4(a3, g.w, w);
    }
    float4 bb = *(const float4*)(bp + j);
    a0.x += bb.x; a0.y += bb.y; a0.z += bb.z; a0.w += bb.w;
    a1.x += bb.x; a1.y += bb.y; a1.z += bb.z; a1.w += bb.w;
    a2.x += bb.x; a2.y += bb.y; a2.z += bb.z; a2.w += bb.w;
    a3.x += bb.x; a3.y += bb.y; a3.z += bb.z; a3.w += bb.w;
    float* ob = out + (mat == 0 ? (size_t)NB * CP * NC : (size_t)0) + (size_t)b * CP * NC;
    int i = i0 + it * 4;
    if (i + 0 < CP) *(float4*)(ob + (size_t)(i + 0) * NC + j) = a0;
    if (i + 1 < CP) *(float4*)(ob + (size_t)(i + 1) * NC + j) = a1;
    if (i + 2 < CP) *(float4*)(ob + (size_t)(i + 2) * NC + j) = a2;
    if (i + 3 < CP) *(float4*)(ob + (size_t)(i + 3) * NC + j) = a3;
}

extern "C" void kernel_launch(void* const* d_in, const int* in_sizes, int n_in,
                              void* d_out, int out_size, void* d_ws, size_t ws_size,
                              hipStream_t stream) {
    const float* x1 = (const float*)d_in[0];
    const float* x2 = (const float*)d_in[1];
    const float* corr = (const float*)d_in[2];
    const float* Wp = (const float*)d_in[3];
    const float* bp = (const float*)d_in[4];
    float* out = (float*)d_out;
    float* w = (float*)d_ws;

    const size_t XSZ = (size_t)NB * KG * XW * 8;   // shorts per frag array = 6,488,064

    size_t o = 0;
    float* rm = w + o;    o += NB * NN;
    float* irs = w + o;   o += NB * NN;
    float* cc = w + o;    o += NB * NN;
    float* pM = w + o;    o += 8 * NB * NN;
    float* pS = w + o;    o += 8 * NB * NN;
    short* Xh = (short*)(w + o); o += XSZ / 2;
    short* Xl = (short*)(w + o); o += XSZ / 2;
    short* Zh = (short*)(w + o); o += XSZ / 2;
    short* Zl = (short*)(w + o); o += XSZ / 2;
    float* Mpart = w + o; o += (size_t)8 * K3S * MD * MD;
    float* M = w + o;     o += (size_t)8 * MD * MD;
    // total ~17.4M floats (~69.4 MB)

    k_prep<<<dim3(3168), dim3(256), 0, stream>>>(x1, x2, Xh, Xl);
    k_rowstats<<<dim3(NN, NB), dim3(256), 0, stream>>>(corr, rm, irs);
    k_colstats<<<dim3(12, NB, 8), dim3(256), 0, stream>>>(corr, pM, pS);
    k_colcombine<<<dim3(48), dim3(256), 0, stream>>>(pM, pS, cc);
    k2_mfma<<<dim3(768), dim3(256), 0, stream>>>(corr, Xh, Xl, rm, irs, cc, Zh, Zl);
    k3_mfma<<<dim3(9, 8, K3S), dim3(256), 0, stream>>>(Xh, Xl, Zh, Zl, Mpart);
    k_mcombine<<<dim3(578), dim3(256), 0, stream>>>(Mpart, M);
    k4_proj<<<dim3(17, NB, 2), dim3(256), 0, stream>>>(M, Wp, bp, out);
}

// Round 4
// 248.105 us; speedup vs baseline: 6.2252x; 1.2017x over previous
//
#include <hip/hip_runtime.h>
#include <math.h>

// Problem constants
#define NB 4        // batch
#define NN 3072     // N = 48*64
#define NC 256      // C
#define CP 262      // C+6
#define KG 384      // NN/8 k-groups
#define XW 528      // frag-array col width: x1(0..255) x2(256..511) pos/P(512..527)
#define MD 272      // padded M dim (17 frags * 16)
#define K3S 8       // k3 split-K
#define HH 48
#define WW 64
#define LOG2E 1.4426950408889634f

typedef short short8 __attribute__((ext_vector_type(8)));
typedef short short4v __attribute__((ext_vector_type(4)));
typedef float f32x4 __attribute__((ext_vector_type(4)));
typedef unsigned int uint4v __attribute__((ext_vector_type(4)));

__device__ __forceinline__ float fexp2(float x) {
#if __has_builtin(__builtin_amdgcn_exp2f)
    return __builtin_amdgcn_exp2f(x);
#else
    return __exp2f(x);
#endif
}

__device__ __forceinline__ void bsplit(float v, short& h, short& l) {
    unsigned u = __float_as_uint(v);
    h = (short)(u >> 16);
    float r = v - __uint_as_float(u & 0xFFFF0000u);
    l = (short)(__float_as_uint(r) >> 16);
}

__device__ __forceinline__ void fma4(float4& c, float a, float4 b) {
    c.x = fmaf(a, b.x, c.x);
    c.y = fmaf(a, b.y, c.y);
    c.z = fmaf(a, b.z, c.z);
    c.w = fmaf(a, b.w, c.w);
}

// ---------------- prep: X=[x1|x2|pos] -> bf16 hi/lo in MFMA-frag order ----------------
// Layout: [b][kg=n/8][col 0..527][j=n%8]
__global__ __launch_bounds__(256) void k_prep(const float* __restrict__ x1,
                                              const float* __restrict__ x2,
                                              short* __restrict__ Xh, short* __restrict__ Xl) {
    int id = blockIdx.x * 256 + threadIdx.x;      // NB*KG*XW = 811008
    if (id >= NB * KG * XW) return;
    int col = id % XW;
    int rest = id / XW;
    int kg = rest % KG;
    int b = rest / KG;
    short* ph = Xh + (size_t)id * 8;
    short* pl = Xl + (size_t)id * 8;
    if (col < 512) {
        const float* src = (col < 256 ? x1 : x2) + ((size_t)b * NN + kg * 8) * NC + (col & 255);
#pragma unroll
        for (int j = 0; j < 8; j++) {
            short hs, ls;
            bsplit(src[(size_t)j * NC], hs, ls);
            ph[j] = hs; pl[j] = ls;
        }
    } else {
        int c = col - 512;
#pragma unroll
        for (int j = 0; j < 8; j++) {
            int k = kg * 8 + j;
            int ip4 = k / HH;
            int ip3 = k - ip4 * HH;
            float p3 = -1.f + 2.f * (float)ip3 / 47.f;
            float p4 = -1.f + 2.f * (float)ip4 / 63.f;
            float v = 0.f;
            if (c == 0) v = p3 * p3;
            else if (c == 1) v = p4 * p4;
            else if (c == 2) v = p3 * p4;
            else if (c == 3) v = p3;
            else if (c == 4) v = p4;
            else if (c == 5) v = 1.f;
            short hs, ls;
            bsplit(v, hs, ls);
            ph[j] = hs; pl[j] = ls;
        }
    }
}

// ---------------- fused stats: col-role (bid<384) + row-role ----------------
// col-role: online (max,sum) partials over 384-row chunks, ILP-4 chains
// row-role: rowmax/rowsum -> rmS = rowmax*log2e, irs = 1/rowsum
__global__ __launch_bounds__(256) void k_stats(const float* __restrict__ corr,
                                               float* __restrict__ pM, float* __restrict__ pS,
                                               float* __restrict__ rmS, float* __restrict__ irs) {
    int bid = blockIdx.x;
    int t = threadIdx.x;
    __shared__ float red[8];
    if (bid < 384) {
        int cx = bid % 12;
        int b = (bid / 12) & 3;
        int ch = bid / 48;
        int m = cx * 256 + t;
        const float* p = corr + (size_t)b * NN * NN + (size_t)ch * 384 * NN + m;
        float mx[4], s[4];
#pragma unroll
        for (int i = 0; i < 4; i++) { mx[i] = -3.4e38f; s[i] = 0.f; }
        for (int r = 0; r < 384; r += 4) {
#pragma unroll
            for (int i = 0; i < 4; i++) {
                float x = p[(size_t)(r + i) * NN];
                float mn = fmaxf(mx[i], x);
                s[i] = s[i] * __expf(mx[i] - mn) + __expf(x - mn);
                mx[i] = mn;
            }
        }
        float mn01 = fmaxf(mx[0], mx[1]);
        float s01 = s[0] * __expf(mx[0] - mn01) + s[1] * __expf(mx[1] - mn01);
        float mn23 = fmaxf(mx[2], mx[3]);
        float s23 = s[2] * __expf(mx[2] - mn23) + s[3] * __expf(mx[3] - mn23);
        float mnA = fmaxf(mn01, mn23);
        float sA = s01 * __expf(mn01 - mnA) + s23 * __expf(mn23 - mnA);
        pM[((size_t)ch * NB + b) * NN + m] = mnA;
        pS[((size_t)ch * NB + b) * NN + m] = sA;
    } else {
        int rid = bid - 384;
        int b = rid / NN;
        int n = rid - b * NN;
        const float4* p = (const float4*)(corr + ((size_t)b * NN + n) * NN);
        float4 v[3];
        float m = -3.4e38f;
#pragma unroll
        for (int i = 0; i < 3; i++) {
            v[i] = p[t + i * 256];
            m = fmaxf(m, fmaxf(fmaxf(v[i].x, v[i].y), fmaxf(v[i].z, v[i].w)));
        }
#pragma unroll
        for (int off = 32; off; off >>= 1) m = fmaxf(m, __shfl_xor(m, off));
        if ((t & 63) == 0) red[t >> 6] = m;
        __syncthreads();
        m = fmaxf(fmaxf(red[0], red[1]), fmaxf(red[2], red[3]));
        float s = 0.f;
#pragma unroll
        for (int i = 0; i < 3; i++)
            s += __expf(v[i].x - m) + __expf(v[i].y - m) + __expf(v[i].z - m) + __expf(v[i].w - m);
#pragma unroll
        for (int off = 32; off; off >>= 1) s += __shfl_xor(s, off);
        if ((t & 63) == 0) red[4 + (t >> 6)] = s;
        __syncthreads();
        if (t == 0) {
            float st = red[4] + red[5] + red[6] + red[7];
            rmS[b * NN + n] = m * LOG2E;
            irs[b * NN + n] = 1.f / st;
        }
    }
}

// ---------------- combine col partials: ccS = (colmax + log(colsum)) * log2e ----------------
__global__ __launch_bounds__(256) void k_colcombine(const float* __restrict__ pM,
                                                    const float* __restrict__ pS,
                                                    float* __restrict__ ccS) {
    int idx = blockIdx.x * 256 + threadIdx.x;
    if (idx >= NB * NN) return;
    float mx = -3.4e38f, s = 0.f;
#pragma unroll
    for (int ch = 0; ch < 8; ch++) {
        float m2 = pM[(size_t)ch * NB * NN + idx];
        float s2 = pS[(size_t)ch * NB * NN + idx];
        float mn = fmaxf(mx, m2);
        s = s * __expf(mx - mn) + s2 * __expf(m2 - mn);
        mx = mn;
    }
    ccS[idx] = (mx + logf(s)) * LOG2E;
}

// ---------------- fused MFMA A-GEMM ----------------
// A[n,m] = exp2(2L*a - rmS[n] - ccS[m]) * irs[n] (irs at epilogue). Split-bf16 3-pass.
// BM=96, BN=256(+16 pos), BK=64. 256 blocks (1/CU), 512 threads (8 waves).
// rg = w&1 (rows rg*48..+48, 3 frags), cg = w>>1 (cols cg*64..+64, 4 frags).
// Waves 0-5 stage A (exp+split) into swizzled LDS; waves 6,7 carry the pos frag MFMAs.
#define MFMA_CLUSTER(AHF, ALF, BHF, BLF)                                                          \
    {                                                                                             \
        _Pragma("unroll") for (int fr_ = 0; fr_ < 3; fr_++)                                       \
        _Pragma("unroll") for (int i_ = 0; i_ < 4; i_++)                                          \
            acc[fr_][i_] = __builtin_amdgcn_mfma_f32_16x16x32_bf16(AHF[fr_], BHF[i_], acc[fr_][i_], 0, 0, 0); \
        _Pragma("unroll") for (int fr_ = 0; fr_ < 3; fr_++)                                       \
        _Pragma("unroll") for (int i_ = 0; i_ < 4; i_++)                                          \
            acc[fr_][i_] = __builtin_amdgcn_mfma_f32_16x16x32_bf16(AHF[fr_], BLF[i_], acc[fr_][i_], 0, 0, 0); \
        _Pragma("unroll") for (int fr_ = 0; fr_ < 3; fr_++)                                       \
        _Pragma("unroll") for (int i_ = 0; i_ < 4; i_++)                                          \
            acc[fr_][i_] = __builtin_amdgcn_mfma_f32_16x16x32_bf16(ALF[fr_], BHF[i_], acc[fr_][i_], 0, 0, 0); \
    }

#define POS_CLUSTER(AHF, ALF, PBH, PBL)                                                           \
    {                                                                                             \
        _Pragma("unroll") for (int fr_ = 0; fr_ < 3; fr_++) {                                     \
            accP[fr_] = __builtin_amdgcn_mfma_f32_16x16x32_bf16(AHF[fr_], (PBH), accP[fr_], 0, 0, 0); \
            accP[fr_] = __builtin_amdgcn_mfma_f32_16x16x32_bf16(AHF[fr_], (PBL), accP[fr_], 0, 0, 0); \
            accP[fr_] = __builtin_amdgcn_mfma_f32_16x16x32_bf16(ALF[fr_], (PBH), accP[fr_], 0, 0, 0); \
        }                                                                                         \
    }

#define READ_AFRAGS(BUFH, BUFL, UNIT, AHF, ALF)                                                   \
    {                                                                                             \
        _Pragma("unroll") for (int fr_ = 0; fr_ < 3; fr_++) {                                     \
            int rowr_ = rbase + fr_ * 16 + row16;                                                 \
            int uidx_ = rowr_ * 32 + (((UNIT) ^ (rowr_ & 7)) << 2);                               \
            AHF[fr_] = *(const short8*)&(BUFH)[uidx_];                                            \
            ALF[fr_] = *(const short8*)&(BUFL)[uidx_];                                            \
        }                                                                                         \
    }

#define LOAD_B(PH, PL, BHF, BLF)                                                                  \
    {                                                                                             \
        _Pragma("unroll") for (int i_ = 0; i_ < 4; i_++) {                                        \
            BHF[i_] = *(const short8*)((PH) + i_ * 128);                                          \
            BLF[i_] = *(const short8*)((PL) + i_ * 128);                                          \
        }                                                                                         \
    }

#define STAGE_A(DSTH, DSTL, PC)                                                                   \
    {                                                                                             \
        f32x4 ccv0 = *(const f32x4*)&ccsh[(PC) * 64 + g * 16];                                    \
        f32x4 ccv1 = *(const f32x4*)&ccsh[(PC) * 64 + g * 16 + 4];                                \
        f32x4 ccv2 = *(const f32x4*)&ccsh[(PC) * 64 + g * 16 + 8];                                \
        f32x4 ccv3 = *(const f32x4*)&ccsh[(PC) * 64 + g * 16 + 12];                               \
        float ev[16];                                                                             \
        _Pragma("unroll") for (int q_ = 0; q_ < 4; q_++) {                                        \
            ev[q_]      = fexp2(fmaf(C2, cr[0][q_], rmn) - ccv0[q_]);                             \
            ev[4 + q_]  = fexp2(fmaf(C2, cr[1][q_], rmn) - ccv1[q_]);                             \
            ev[8 + q_]  = fexp2(fmaf(C2, cr[2][q_], rmn) - ccv2[q_]);                             \
            ev[12 + q_] = fexp2(fmaf(C2, cr[3][q_], rmn) - ccv3[q_]);                             \
        }                                                                                         \
        uint4v hi0, hi1, lo0, lo1;                                                                \
        _Pragma("unroll") for (int q_ = 0; q_ < 4; q_++) {                                        \
            unsigned u0 = __float_as_uint(ev[2 * q_]);                                            \
            unsigned u1 = __float_as_uint(ev[2 * q_ + 1]);                                        \
            hi0[q_] = __builtin_amdgcn_perm(u1, u0, 0x07060302u);                                 \
            float r0_ = ev[2 * q_] - __uint_as_float(u0 & 0xffff0000u);                           \
            float r1_ = ev[2 * q_ + 1] - __uint_as_float(u1 & 0xffff0000u);                       \
            lo0[q_] = __builtin_amdgcn_perm(__float_as_uint(r1_), __float_as_uint(r0_), 0x07060302u); \
            unsigned v0 = __float_as_uint(ev[8 + 2 * q_]);                                        \
            unsigned v1 = __float_as_uint(ev[8 + 2 * q_ + 1]);                                    \
            hi1[q_] = __builtin_amdgcn_perm(v1, v0, 0x07060302u);                                 \
            float t0_ = ev[8 + 2 * q_] - __uint_as_float(v0 & 0xffff0000u);                       \
            float t1_ = ev[8 + 2 * q_ + 1] - __uint_as_float(v1 & 0xffff0000u);                   \
            lo1[q_] = __builtin_amdgcn_perm(__float_as_uint(t1_), __float_as_uint(t0_), 0x07060302u); \
        }                                                                                         \
        *(uint4v*)&(DSTH)[widx0] = hi0;                                                           \
        *(uint4v*)&(DSTH)[widx1] = hi1;                                                           \
        *(uint4v*)&(DSTL)[widx0] = lo0;                                                           \
        *(uint4v*)&(DSTL)[widx1] = lo1;                                                           \
    }

__global__ __launch_bounds__(512, 2) void k2_mfma(const float* __restrict__ corr,
        const short* __restrict__ Xh, const short* __restrict__ Xl,
        const float* __restrict__ rmS, const float* __restrict__ irs,
        const float* __restrict__ ccS,
        short* __restrict__ Zh, short* __restrict__ Zl) {
    __shared__ __align__(16) unsigned AHs[2][96 * 32];   // bf16-hi A tile, [buf][row*32 + swz16unit*4 + w]
    __shared__ __align__(16) unsigned ALs[2][96 * 32];
    __shared__ __align__(16) float ccsh[NN];

    const float C2 = 2.f * LOG2E;
    const size_t BSTEP = (size_t)4 * XW * 8;   // advance 4 kg (one K=32 half)

    int bid = blockIdx.x;                    // 256 = 8 xcd * 32
    int xcd = bid & 7, sub = bid >> 3;       // sub 0..31
    int b = xcd >> 1;                        // batch on XCD pair
    int which = sub & 1;                     // twins (same rows, other X half) on same XCD
    int rowblk = (xcd & 1) + ((sub >> 1) << 1);   // 0..31
    int n0 = rowblk * 96;

    int t = threadIdx.x;
    int w = t >> 6, l = t & 63;
    int row16 = l & 15, slot = l >> 4;
    int rg = w & 1, cg = w >> 1;             // rows rg*48..+48, cols cg*64..+64
    int rbase = rg * 48;
    bool posw = (which == 0) && (cg == 3);   // waves 6,7
    bool writer = (t < 384);                 // waves 0..5
    int wrow = t >> 2, g = t & 3;            // writer: row 0..95, k-16-group 0..3
    int widx0 = wrow * 32 + (((2 * g) ^ (wrow & 7)) << 2);
    int widx1 = wrow * 32 + (((2 * g + 1) ^ (wrow & 7)) << 2);

    // stage ccS into LDS
    {
        const f32x4* src = (const f32x4*)(ccS + (size_t)b * NN);
        for (int i = t; i < NN / 4; i += 512) ((f32x4*)ccsh)[i] = src[i];
    }

    const float* corrR = corr;
    float rmn = 0.f;
    if (writer) {
        corrR = corr + ((size_t)b * NN + n0 + wrow) * NN + g * 16;
        rmn = -rmS[b * NN + n0 + wrow];
    }

    // B pointers (frag-direct), kg = slot initially
    int col0 = which * 256 + cg * 64 + row16;
    const short* bh = Xh + ((size_t)(b * KG + slot) * XW + col0) * 8;
    const short* bl = Xl + ((size_t)(b * KG + slot) * XW + col0) * 8;
    const short* ph = Xh + ((size_t)(b * KG + slot) * XW + 512 + row16) * 8;
    const short* plp = Xl + ((size_t)(b * KG + slot) * XW + 512 + row16) * 8;

    f32x4 acc[3][4];
    f32x4 accP[3];
    const f32x4 zz = {0.f, 0.f, 0.f, 0.f};
#pragma unroll
    for (int fr = 0; fr < 3; fr++) {
#pragma unroll
        for (int i = 0; i < 4; i++) acc[fr][i] = zz;
        accP[fr] = zz;
    }

    // prologue: B(kk0, phase0)
    short8 BhA[4], BlA[4], BhB[4], BlB[4];
    short8 PbhA = {0,0,0,0,0,0,0,0}, PblA = PbhA, PbhB = PbhA, PblB = PbhA;
    LOAD_B(bh, bl, BhA, BlA);
    if (posw) { PbhA = *(const short8*)ph; PblA = *(const short8*)plp; }

    f32x4 cr[4];
    __syncthreads();   // ccsh ready
    if (writer) {
#pragma unroll
        for (int q = 0; q < 4; q++) cr[q] = *(const f32x4*)(corrR + q * 4);
        STAGE_A(AHs[0], ALs[0], 0);
#pragma unroll
        for (int q = 0; q < 4; q++) cr[q] = *(const f32x4*)(corrR + 64 + q * 4);
    }
    asm volatile("s_waitcnt lgkmcnt(0)" ::: "memory");
    __builtin_amdgcn_s_barrier();

    int cur = 0;
    for (int p = 0; p < 48; ++p) {
        const unsigned* AHc = &AHs[cur][0];
        const unsigned* ALc = &ALs[cur][0];
        unsigned* AHn = &AHs[cur ^ 1][0];
        unsigned* ALn = &ALs[cur ^ 1][0];
        short8 Ah[3], Al[3];
        // ---- kk0 ----
        READ_AFRAGS(AHc, ALc, slot, Ah, Al);
        bh += BSTEP; bl += BSTEP;
        LOAD_B(bh, bl, BhB, BlB);
        if (posw) { ph += BSTEP; plp += BSTEP; PbhB = *(const short8*)ph; PblB = *(const short8*)plp; }
        MFMA_CLUSTER(Ah, Al, BhA, BlA);
        if (posw) POS_CLUSTER(Ah, Al, PbhA, PblA);
        // ---- kk1 ----
        READ_AFRAGS(AHc, ALc, 4 + slot, Ah, Al);
        if (p < 47) {
            bh += BSTEP; bl += BSTEP;
            LOAD_B(bh, bl, BhA, BlA);
            if (posw) { ph += BSTEP; plp += BSTEP; PbhA = *(const short8*)ph; PblA = *(const short8*)plp; }
        }
        if (writer) {
            int pc = (p + 1 < 48) ? p + 1 : 47;
            STAGE_A(AHn, ALn, pc);
            int pn = (p + 2 < 48) ? p + 2 : 47;
#pragma unroll
            for (int q = 0; q < 4; q++) cr[q] = *(const f32x4*)(corrR + pn * 64 + q * 4);
        }
        MFMA_CLUSTER(Ah, Al, BhB, BlB);
        if (posw) POS_CLUSTER(Ah, Al, PbhB, PblB);
        asm volatile("s_waitcnt lgkmcnt(0)" ::: "memory");
        __builtin_amdgcn_s_barrier();
        cur ^= 1;
    }

    // epilogue: scale by 1/rowsum, bf16-split, write frag-layout Zarr
#pragma unroll
    for (int fr = 0; fr < 3; fr++) {
        f32x4 sv = *(const f32x4*)(irs + b * NN + n0 + rbase + fr * 16 + slot * 4);
        int kgz = rowblk * 12 + rg * 6 + fr * 2 + (slot >> 1);
        int jb = (slot & 1) << 2;
#pragma unroll
        for (int i = 0; i < 4; i++) {
            int colv = which * 256 + cg * 64 + i * 16 + row16;
            size_t off = ((size_t)(b * KG + kgz) * XW + colv) * 8 + jb;
            short4v zh, zl;
#pragma unroll
            for (int r = 0; r < 4; r++) {
                float vv = acc[fr][i][r] * sv[r];
                short hs, ls; bsplit(vv, hs, ls);
                zh[r] = hs; zl[r] = ls;
            }
            *(short4v*)(Zh + off) = zh;
            *(short4v*)(Zl + off) = zl;
        }
        if (posw && cg == 3 && rg == (w & 1)) { /* waves 6,7 */ }
        if (posw) {
            size_t off = ((size_t)(b * KG + kgz) * XW + 512 + row16) * 8 + jb;
            short4v zh, zl;
#pragma unroll
            for (int r = 0; r < 4; r++) {
                float vv = accP[fr][r] * sv[r];
                short hs, ls; bsplit(vv, hs, ls);
                zh[r] = hs; zl[r] = ls;
            }
            *(short4v*)(Zh + off) = zh;
            *(short4v*)(Zl + off) = zl;
        }
    }
}

// ---------------- k3: M[r][c] = sum_n L[n][r] R[n][c] via MFMA (split-bf16, split-K=8) -------
__global__ __launch_bounds__(256) void k3_mfma(const short* __restrict__ Xh, const short* __restrict__ Xl,
                                               const short* __restrict__ Zh, const short* __restrict__ Zl,
                                               float* __restrict__ Mpart) {
    int tile = blockIdx.x;              // 0..8 (3x3 frag tiles of [6,6,5])
    int rt = tile / 3, ct = tile % 3;
    int mb = blockIdx.y;                // mat*4+b
    int mat = mb >> 2, b = mb & 3;
    int split = blockIdx.z;             // 0..7, 48 kg each

    const int O0[4] = {0, 6, 12, 17};
    int r0f = O0[rt], rNf = O0[rt + 1] - r0f;
    int c0f = O0[ct], cNf = O0[ct + 1] - c0f;

    int t = threadIdx.x;
    int w = t >> 6, l = t & 63;
    int row16 = l & 15, slot = l >> 4;
    int wr = w >> 1, wc = w & 1;
    int rh = (rNf + 1) >> 1;
    int rbeg = r0f + (wr ? rh : 0);
    int rcnt = wr ? (rNf - rh) : rh;
    int chh = (cNf + 1) >> 1;
    int cbeg = c0f + (wc ? chh : 0);
    int ccnt = wc ? (cNf - chh) : chh;

    const short *Ah_, *Al_, *Bh_, *Bl_;
    int abase, bbase;
    if (mat == 0) { Ah_ = Xh; Al_ = Xl; Bh_ = Zh; Bl_ = Zl; abase = 0; bbase = 0; }
    else          { Ah_ = Zh; Al_ = Zl; Bh_ = Xh; Bl_ = Xl; abase = 256; bbase = 256; }

    int acol[3], bcol[3];
#pragma unroll
    for (int i = 0; i < 3; i++) {
        int fa = rbeg + i;
        acol[i] = ((fa < 16) ? (abase + fa * 16) : 512) + row16;
        int fb = cbeg + i;
        bcol[i] = ((fb < 16) ? (bbase + fb * 16) : 512) + row16;
    }

    f32x4 acc[3][3];
    const f32x4 zz = {0.f, 0.f, 0.f, 0.f};
#pragma unroll
    for (int i = 0; i < 3; i++)
#pragma unroll
        for (int j = 0; j < 3; j++) acc[i][j] = zz;

    for (int it = 0; it < 12; it++) {
        int kg = split * 48 + it * 4 + slot;
        size_t base = (size_t)(b * KG + kg) * XW;
        short8 Ah[3], Al[3], Bhf[3], Blf[3];
#pragma unroll
        for (int i = 0; i < 3; i++) {
            if (i < rcnt) {
                Ah[i] = *(const short8*)(Ah_ + (base + acol[i]) * 8);
                Al[i] = *(const short8*)(Al_ + (base + acol[i]) * 8);
            }
            if (i < ccnt) {
                Bhf[i] = *(const short8*)(Bh_ + (base + bcol[i]) * 8);
                Blf[i] = *(const short8*)(Bl_ + (base + bcol[i]) * 8);
            }
        }
#pragma unroll
        for (int i = 0; i < 3; i++) {
            if (i < rcnt) {
#pragma unroll
                for (int j = 0; j < 3; j++) {
                    if (j < ccnt) {
                        acc[i][j] = __builtin_amdgcn_mfma_f32_16x16x32_bf16(Ah[i], Bhf[j], acc[i][j], 0, 0, 0);
                        acc[i][j] = __builtin_amdgcn_mfma_f32_16x16x32_bf16(Al[i], Bhf[j], acc[i][j], 0, 0, 0);
                        acc[i][j] = __builtin_amdgcn_mfma_f32_16x16x32_bf16(Ah[i], Blf[j], acc[i][j], 0, 0, 0);
                    }
                }
            }
        }
    }

    float* Mp = Mpart + (size_t)(mb * K3S + split) * (MD * MD);
#pragma unroll
    for (int i = 0; i < 3; i++) {
        if (i < rcnt) {
#pragma unroll
            for (int j = 0; j < 3; j++) {
                if (j < ccnt) {
                    int r = (rbeg + i) * 16 + slot * 4;
                    int c = (cbeg + j) * 16 + row16;
#pragma unroll
                    for (int q = 0; q < 4; q++)
                        Mp[(size_t)(r + q) * MD + c] = acc[i][j][q];
                }
            }
        }
    }
}

// ---------------- combine M split partials ----------------
__global__ __launch_bounds__(256) void k_mcombine(const float* __restrict__ Mpart, float* __restrict__ M) {
    const int per = MD * MD;  // 73984
    int f4 = blockIdx.x * 256 + threadIdx.x;
    if (f4 >= (8 * per) / 4) return;
    int e = f4 * 4;
    int mb = e / per;
    int off = e - mb * per;
    const float* src = Mpart + (size_t)mb * K3S * per + off;
    float4 s = make_float4(0.f, 0.f, 0.f, 0.f);
#pragma unroll
    for (int sp = 0; sp < K3S; sp++) {
        float4 v = *(const float4*)(src + (size_t)sp * per);
        s.x += v.x; s.y += v.y; s.z += v.z; s.w += v.w;
    }
    *(float4*)(M + (size_t)mb * per + off) = s;
}

// ---------------- projection: out[i][j] = b[j] + sum_k M[k][i] W[k][j] ----------------
__global__ __launch_bounds__(256) void k4_proj(const float* __restrict__ M, const float* __restrict__ Wp,
                                               const float* __restrict__ bp, float* __restrict__ out) {
    int i0 = blockIdx.x * 16;
    int b = blockIdx.y;
    int mat = blockIdx.z;
    const float* Mp = M + (size_t)(mat * 4 + b) * (MD * MD);
    int t = threadIdx.x;
    int jt = t & 63, it = t >> 6;
    int j = jt * 4;
    float4 a0 = make_float4(0.f, 0.f, 0.f, 0.f), a1 = a0, a2 = a0, a3 = a0;
#pragma unroll 2
    for (int k = 0; k < CP; k++) {
        float4 w = *(const float4*)(Wp + (size_t)k * NC + j);
        float4 g = *(const float4*)(Mp + (size_t)k * MD + i0 + it * 4);
        fma4(a0, g.x, w); fma4(a1, g.y, w); fma4(a2, g.z, w); fma4(a3, g.w, w);
    }
    float4 bb = *(const float4*)(bp + j);
    a0.x += bb.x; a0.y += bb.y; a0.z += bb.z; a0.w += bb.w;
    a1.x += bb.x; a1.y += bb.y; a1.z += bb.z; a1.w += bb.w;
    a2.x += bb.x; a2.y += bb.y; a2.z += bb.z; a2.w += bb.w;
    a3.x += bb.x; a3.y += bb.y; a3.z += bb.z; a3.w += bb.w;
    float* ob = out + (mat == 0 ? (size_t)NB * CP * NC : (size_t)0) + (size_t)b * CP * NC;
    int i = i0 + it * 4;
    if (i + 0 < CP) *(float4*)(ob + (size_t)(i + 0) * NC + j) = a0;
    if (i + 1 < CP) *(float4*)(ob + (size_t)(i + 1) * NC + j) = a1;
    if (i + 2 < CP) *(float4*)(ob + (size_t)(i + 2) * NC + j) = a2;
    if (i + 3 < CP) *(float4*)(ob + (size_t)(i + 3) * NC + j) = a3;
}

extern "C" void kernel_launch(void* const* d_in, const int* in_sizes, int n_in,
                              void* d_out, int out_size, void* d_ws, size_t ws_size,
                              hipStream_t stream) {
    const float* x1 = (const float*)d_in[0];
    const float* x2 = (const float*)d_in[1];
    const float* corr = (const float*)d_in[2];
    const float* Wp = (const float*)d_in[3];
    const float* bp = (const float*)d_in[4];
    float* out = (float*)d_out;
    float* w = (float*)d_ws;

    const size_t XSZ = (size_t)NB * KG * XW * 8;   // shorts per frag array = 6,488,064

    size_t o = 0;
    float* rmS = w + o;   o += NB * NN;
    float* irs = w + o;   o += NB * NN;
    float* ccS = w + o;   o += NB * NN;
    float* pM = w + o;    o += 8 * NB * NN;
    float* pS = w + o;    o += 8 * NB * NN;
    short* Xh = (short*)(w + o); o += XSZ / 2;
    short* Xl = (short*)(w + o); o += XSZ / 2;
    short* Zh = (short*)(w + o); o += XSZ / 2;
    short* Zl = (short*)(w + o); o += XSZ / 2;
    float* Mpart = w + o; o += (size_t)8 * K3S * MD * MD;
    float* M = w + o;     o += (size_t)8 * MD * MD;
    // total ~18.6M floats (~74 MB)

    k_prep<<<dim3(3168), dim3(256), 0, stream>>>(x1, x2, Xh, Xl);
    k_stats<<<dim3(384 + NB * NN), dim3(256), 0, stream>>>(corr, pM, pS, rmS, irs);
    k_colcombine<<<dim3(48), dim3(256), 0, stream>>>(pM, pS, ccS);
    k2_mfma<<<dim3(256), dim3(512), 0, stream>>>(corr, Xh, Xl, rmS, irs, ccS, Zh, Zl);
    k3_mfma<<<dim3(9, 8, K3S), dim3(256), 0, stream>>>(Xh, Xl, Zh, Zl, Mpart);
    k_mcombine<<<dim3(578), dim3(256), 0, stream>>>(Mpart, M);
    k4_proj<<<dim3(17, NB, 2), dim3(256), 0, stream>>>(M, Wp, bp, out);
}